// Round 8
// baseline (1867.357 us; speedup 1.0000x reference)
//
#include <hip/hip_runtime.h>
#include <math.h>

#define NN 4096
#define BB 4
#define NPT (NN*BB)
#define KK 20
#define EPSB 1e-5f

#define AS_STRIDE 132   // 128-point c-row, padded
#define WS_STRIDE 68    // 64-col c-row, padded
// Non-wrapping per-channel skew: staging writes 2-way (free), reads clean,
// all offsets multiples of 4 floats so float4 reads stay 16B-aligned.
#define SKEW(c) ((((((c)>>2)&7))<<2) + (((c)>>5)*28))

__device__ __forceinline__ float lrelu(float x){ return x >= 0.f ? x : 0.2f*x; }

// monotone float->uint key: order(key) == order(float)
__device__ __forceinline__ unsigned fkey(float x){
  unsigned u = __float_as_uint(x);
  return u ^ (unsigned)(((int)u >> 31) | 0x80000000);
}

// ---- stage 1: conv1 (3->64), writes raw into xcat[:, 0:64] (point-major, row stride 192)
__global__ void conv1_kernel(const float* __restrict__ x, const float* __restrict__ W1,
                             float* __restrict__ xcat){
  __shared__ float Wl[192];
  int tid = threadIdx.x;
  if (tid < 192) Wl[tid] = W1[tid];
  __syncthreads();
  int p = blockIdx.x*4 + (tid >> 6);
  int o = tid & 63;
  int b = p >> 12, n = p & 4095;
  const float* xb = x + (size_t)b*3*NN + n;
  float acc = Wl[o*3+0]*xb[0] + Wl[o*3+1]*xb[NN] + Wl[o*3+2]*xb[2*NN];
  xcat[(size_t)p*192 + o] = acc;
}

// ---- per-channel partial stats for point-major (NPT, C) buffer; deterministic slots
__global__ void stats_pm_kernel(const float* __restrict__ buf, int stride, int ofs,
                                float* __restrict__ psum, float* __restrict__ psumsq, int C){
  int tid = threadIdx.x;
  int lane = tid & 63, g = tid >> 6;
  int o = blockIdx.x*64 + lane;
  int p0 = blockIdx.y*256 + g*64;
  float s = 0.f, ss = 0.f;
  for (int i = 0; i < 64; ++i){
    float v = buf[(size_t)(p0+i)*stride + ofs + o];
    s += v; ss += v*v;
  }
  __shared__ float rs[4][64], rss[4][64];
  rs[g][lane] = s; rss[g][lane] = ss;
  __syncthreads();
  if (g == 0){
    s  = rs[0][lane]+rs[1][lane]+rs[2][lane]+rs[3][lane];
    ss = rss[0][lane]+rss[1][lane]+rss[2][lane]+rss[3][lane];
    psum[(size_t)blockIdx.y*C + o] = s;
    psumsq[(size_t)blockIdx.y*C + o] = ss;
  }
}

// deterministic finalize: serial sum over nparts partials per channel
__global__ void bn_finalize_kernel(const float* __restrict__ psum, const float* __restrict__ psumsq,
                                   int nparts,
                                   const float* __restrict__ gamma, const float* __restrict__ beta,
                                   float* __restrict__ scale, float* __restrict__ shift,
                                   float invcnt, int C){
  int o = threadIdx.x + blockIdx.x*blockDim.x;
  if (o >= C) return;
  float s = 0.f, ss = 0.f;
  for (int i = 0; i < nparts; ++i){
    s  += psum[(size_t)i*C + o];
    ss += psumsq[(size_t)i*C + o];
  }
  float m = s*invcnt;
  float v = ss*invcnt - m*m;
  v = fmaxf(v, 0.f);
  float sc = gamma[o] * rsqrtf(v + EPSB);
  scale[o] = sc;
  shift[o] = beta[o] - m*sc;
}

__global__ void apply_bn_kernel(float* __restrict__ buf, int stride, int ofs, int log2C,
                                const float* __restrict__ scale, const float* __restrict__ shift){
  int i = blockIdx.x*256 + threadIdx.x;
  int o = i & ((1<<log2C)-1);
  int p = i >> log2C;
  size_t a = (size_t)p*stride + ofs + o;
  float e = buf[a]*scale[o] + shift[o];
  buf[a] = lrelu(e);
}

// ---- ||x||^2 per point (64 features)
__global__ void xx_kernel(const float* __restrict__ xcat, int stride, int ofs,
                          float* __restrict__ xx){
  int p = blockIdx.x*256 + threadIdx.x;
  const float4* r = (const float4*)(xcat + (size_t)p*stride + ofs);
  float s = 0.f;
  #pragma unroll
  for (int i = 0; i < 16; ++i){ float4 v = r[i]; s += v.x*v.x + v.y*v.y + v.z*v.z + v.w*v.w; }
  xx[p] = s;
}

// ---- gmax: TRIANGULAR 128x128 tiles (by<=bx), all batches fused (blockIdx.z).
// Same GEMM + epilogue chains as the verified dist kernel, but dist is NEVER
// stored -- only the per-(row,group-of-8) key-maxima (u32 keys). The topk
// recomputes candidate values with the identical FMA chain, so selection is
// bit-identical. Group gid: cols {cb..cb+3, cb+64..cb+67},
// cb = (gid>>4)*128 + (gid&15)*4. Each (row,gid) written exactly once.
__global__ void __launch_bounds__(256, 2)
gmax_kernel(const float* __restrict__ xcat, int ofs,
            const float* __restrict__ xx, unsigned* __restrict__ gmaxp){
  int bx = blockIdx.x, by = blockIdx.y, b = blockIdx.z;
  if (by > bx) return;                 // lower triangle covered by mirror
  __shared__ float As[64*AS_STRIDE + 64];
  __shared__ float Bs[64*AS_STRIDE + 64];
  int tid = threadIdx.x;
  int n0 = by*128, m0 = bx*128;        // row tile <= col tile
  const float* base = xcat + (size_t)b*NN*192 + ofs;
  int cgrp = (tid & 15)*4;
  float4 vin[8], vw[8];
  #pragma unroll
  for (int j = 0; j < 8; ++j){
    int row = (tid + 256*j) >> 4;
    vin[j] = *(const float4*)(base + (size_t)(n0+row)*192 + cgrp);
    vw[j]  = *(const float4*)(base + (size_t)(m0+row)*192 + cgrp);
  }
  #pragma unroll
  for (int j = 0; j < 8; ++j){
    int row = (tid + 256*j) >> 4, c4 = cgrp;
    float4 v = vin[j];
    As[(c4+0)*AS_STRIDE+SKEW(c4+0)+row]=v.x; As[(c4+1)*AS_STRIDE+SKEW(c4+1)+row]=v.y;
    As[(c4+2)*AS_STRIDE+SKEW(c4+2)+row]=v.z; As[(c4+3)*AS_STRIDE+SKEW(c4+3)+row]=v.w;
    float4 w = vw[j];
    Bs[(c4+0)*AS_STRIDE+SKEW(c4+0)+row]=w.x; Bs[(c4+1)*AS_STRIDE+SKEW(c4+1)+row]=w.y;
    Bs[(c4+2)*AS_STRIDE+SKEW(c4+2)+row]=w.z; Bs[(c4+3)*AS_STRIDE+SKEW(c4+3)+row]=w.w;
  }
  __syncthreads();
  int pA = (tid >> 4)*4, oB = (tid & 15)*4;
  float acc[8][8] = {};   // i: 0-3 rows pA+i, 4-7 rows pA+64+(i-4); j likewise cols
  for (int c = 0; c < 64; ++c){
    const float* arow = &As[c*AS_STRIDE + SKEW(c)];
    const float* brow = &Bs[c*AS_STRIDE + SKEW(c)];
    float4 a0 = *(const float4*)&arow[pA];
    float4 a1 = *(const float4*)&arow[pA + 64];
    float4 b0 = *(const float4*)&brow[oB];
    float4 b1 = *(const float4*)&brow[oB + 64];
    float av[8] = {a0.x,a0.y,a0.z,a0.w,a1.x,a1.y,a1.z,a1.w};
    float bv[8] = {b0.x,b0.y,b0.z,b0.w,b1.x,b1.y,b1.z,b1.w};
    #pragma unroll
    for (int i = 0; i < 8; ++i)
      #pragma unroll
      for (int j = 0; j < 8; ++j)
        acc[i][j] += av[i]*bv[j];
  }
  float xmv[8], xnv[8];
  #pragma unroll
  for (int j = 0; j < 4; ++j){
    xmv[j]   = xx[b*NN + m0 + oB + j];
    xmv[4+j] = xx[b*NN + m0 + 64 + oB + j];
    xnv[j]   = xx[b*NN + n0 + pA + j];
    xnv[4+j] = xx[b*NN + n0 + 64 + pA + j];
  }
  #pragma unroll
  for (int h = 0; h < 2; ++h){
    #pragma unroll
    for (int i = 0; i < 4; ++i){
      int row = n0 + h*64 + pA + i;
      float xn = xnv[h*4 + i];
      int ai = h*4 + i;
      float4 w0, w1;
      w0.x = 2.f*acc[ai][0] - xn - xmv[0]; w0.y = 2.f*acc[ai][1] - xn - xmv[1];
      w0.z = 2.f*acc[ai][2] - xn - xmv[2]; w0.w = 2.f*acc[ai][3] - xn - xmv[3];
      w1.x = 2.f*acc[ai][4] - xn - xmv[4]; w1.y = 2.f*acc[ai][5] - xn - xmv[5];
      w1.z = 2.f*acc[ai][6] - xn - xmv[6]; w1.w = 2.f*acc[ai][7] - xn - xmv[7];
      unsigned gm = fkey(w0.x), t;
      t = fkey(w0.y); if (t > gm) gm = t;
      t = fkey(w0.z); if (t > gm) gm = t;
      t = fkey(w0.w); if (t > gm) gm = t;
      t = fkey(w1.x); if (t > gm) gm = t;
      t = fkey(w1.y); if (t > gm) gm = t;
      t = fkey(w1.z); if (t > gm) gm = t;
      t = fkey(w1.w); if (t > gm) gm = t;
      gmaxp[(size_t)(b*NN + row)*512 + (bx<<4) + (oB>>2)] = gm;
    }
  }
  if (bx != by){
    // mirror: element (m,n) = ((2a - xx[m]) - xx[n])
    #pragma unroll
    for (int jh = 0; jh < 2; ++jh){
      #pragma unroll
      for (int jj = 0; jj < 4; ++jj){
        int j = jh*4 + jj;
        float xm = xmv[j];
        float4 lo, hi;
        lo.x = 2.f*acc[0][j] - xm - xnv[0];
        lo.y = 2.f*acc[1][j] - xm - xnv[1];
        lo.z = 2.f*acc[2][j] - xm - xnv[2];
        lo.w = 2.f*acc[3][j] - xm - xnv[3];
        hi.x = 2.f*acc[4][j] - xm - xnv[4];
        hi.y = 2.f*acc[5][j] - xm - xnv[5];
        hi.z = 2.f*acc[6][j] - xm - xnv[6];
        hi.w = 2.f*acc[7][j] - xm - xnv[7];
        int mrow = m0 + jh*64 + oB + jj;
        unsigned gm = fkey(lo.x), t;
        t = fkey(lo.y); if (t > gm) gm = t;
        t = fkey(lo.z); if (t > gm) gm = t;
        t = fkey(lo.w); if (t > gm) gm = t;
        t = fkey(hi.x); if (t > gm) gm = t;
        t = fkey(hi.y); if (t > gm) gm = t;
        t = fkey(hi.z); if (t > gm) gm = t;
        t = fkey(hi.w); if (t > gm) gm = t;
        gmaxp[(size_t)(b*NN + mrow)*512 + (by<<4) + (pA>>2)] = gm;
      }
    }
  }
}

// ---- topk v4: group-max prefilter + RECOMPUTE candidates (no dist matrix).
// One wave per row, all batches fused (blockIdx.z). T from the shortened
// binary radix (bits 31..16, early exit at <=44 passing groups): T <= exact
// 20th gmax <= v20, so key>=T keeps every top-20 value incl. ties -> exact.
// Candidate values recomputed with the same ascending-c += chain and
// ((2a - xx[row]) - xx[col]) epilogue as gmax_kernel -> bit-identical keys.
// C<=64: 64-lane bitonic sort (value desc, index asc). C>64 (rare): per-lane
// register top-20 over recomputed own-group candidates + 20-round shfl merge.
__global__ void __launch_bounds__(256)
topk_kernel(const float* __restrict__ xcat, int ofs, const float* __restrict__ xx,
            const unsigned* __restrict__ gmax, int* __restrict__ idxout){
  __shared__ unsigned lv[4][256], li[4][256];
  __shared__ unsigned lcnt[4];
  __shared__ float xnl[4][64];
  int wv = threadIdx.x >> 6, lane = threadIdx.x & 63;
  int b = blockIdx.z;
  int n = blockIdx.x*4 + wv;                 // row within batch
  const float* base = xcat + (size_t)b*NN*192 + ofs;
  const unsigned* grow = gmax + (size_t)(b*NN + n)*512;
  unsigned g[8];
  #pragma unroll
  for (int j = 0; j < 8; ++j) g[j] = grow[j*64 + lane];
  xnl[wv][lane] = base[(size_t)n*192 + lane];   // row features (wave-local LDS)
  float xxn = xx[b*NN + n];
  if (lane == 0) lcnt[wv] = 0u;                 // same-wave LDS ops are in-order
  unsigned prefix = 0u, act = 0xFFu; int need = KK; int tot = 512;
  for (int bit = 31; bit >= 16; --bit){
    unsigned m = 0u;
    #pragma unroll
    for (int j = 0; j < 8; ++j) m |= ((g[j] >> bit) & 1u) << j;
    unsigned c = (unsigned)__popc(m & act);
    #pragma unroll
    for (int s = 1; s < 64; s <<= 1) c += __shfl_xor(c, s);
    if ((int)c >= need){ act &= m; prefix |= (1u << bit); tot = (int)c; }
    else { need -= (int)c; act &= ~m; tot -= (int)c; }
    if (KK - need + tot <= 44) break;    // few enough passing groups: stop
  }
  unsigned T = prefix;                    // conservative (<= exact 20th gmax)
  const float* xrow = xnl[wv];
  #pragma unroll
  for (int j = 0; j < 8; ++j){
    if (g[j] >= T){
      int gid = j*64 + lane;
      int cbase = ((gid >> 4) << 7) + ((gid & 15) << 2);
      int mcol[8];
      const float* xmp[8];
      float dacc[8] = {0.f,0.f,0.f,0.f,0.f,0.f,0.f,0.f};
      #pragma unroll
      for (int t = 0; t < 8; ++t){
        mcol[t] = cbase + ((t < 4) ? t : (60 + t));
        xmp[t] = base + (size_t)mcol[t]*192;
      }
      for (int c = 0; c < 64; c += 4){
        float4 a4 = *(const float4*)(xrow + c);
        #pragma unroll
        for (int t = 0; t < 8; ++t){
          float4 b4 = *(const float4*)(xmp[t] + c);
          dacc[t] += a4.x*b4.x; dacc[t] += a4.y*b4.y;
          dacc[t] += a4.z*b4.z; dacc[t] += a4.w*b4.w;
        }
      }
      unsigned keys[8];
      #pragma unroll
      for (int t = 0; t < 8; ++t){
        float dd = 2.f*dacc[t] - xxn - xx[b*NN + mcol[t]];
        keys[t] = fkey(dd);
      }
      int q = 0;
      #pragma unroll
      for (int t = 0; t < 8; ++t) q += (keys[t] >= T);
      unsigned pos = atomicAdd(&lcnt[wv], (unsigned)q);
      #pragma unroll
      for (int t = 0; t < 8; ++t){
        if (keys[t] >= T){
          if (pos < 256u){ lv[wv][pos] = keys[t]; li[wv][pos] = (unsigned)mcol[t]; }
          pos++;
        }
      }
    }
  }
  unsigned C = lcnt[wv];                  // all wave atomics precede this read
  int* orow = idxout + (size_t)(b*NN + n)*KK;
  if (C <= 64u){
    unsigned kv = 0u, ki = 0xFFFFFFFFu;   // dummy key 0 = -inf, never a real dist
    if (lane < (int)C){ kv = lv[wv][lane]; ki = li[wv][lane]; }
    #pragma unroll
    for (int k = 2; k <= 64; k <<= 1){
      #pragma unroll
      for (int j2 = k >> 1; j2 > 0; j2 >>= 1){
        unsigned ov = __shfl_xor(kv, j2);
        unsigned oi = __shfl_xor(ki, j2);
        bool iLower = ((lane & j2) == 0);
        bool dirDesc = ((lane & k) == 0);
        bool mineGr = (kv > ov) || (kv == ov && ki < oi);
        bool keep = dirDesc ? (iLower ? mineGr : !mineGr)
                            : (iLower ? !mineGr : mineGr);
        kv = keep ? kv : ov;
        ki = keep ? ki : oi;
      }
    }
    if (lane < KK) orow[lane] = (int)ki;
  } else {
    // rare exact fallback: recompute own groups, per-lane reg top-20 + merge
    unsigned rv[KK], ri[KK];
    #pragma unroll
    for (int q = 0; q < KK; ++q){ rv[q]=0u; ri[q]=0xFFFFFFFFu; }
    #pragma unroll
    for (int j = 0; j < 8; ++j){
      if (g[j] >= T){
        int gid = j*64 + lane;
        int cbase = ((gid >> 4) << 7) + ((gid & 15) << 2);
        #pragma unroll
        for (int t = 0; t < 8; ++t){
          int m = cbase + ((t < 4) ? t : (60 + t));
          const float* xm = base + (size_t)m*192;
          float dacc = 0.f;
          for (int c = 0; c < 64; c += 4){
            float4 a4 = *(const float4*)(xrow + c);
            float4 b4 = *(const float4*)(xm + c);
            dacc += a4.x*b4.x; dacc += a4.y*b4.y;
            dacc += a4.z*b4.z; dacc += a4.w*b4.w;
          }
          float dd = 2.f*dacc - xxn - xx[b*NN + m];
          unsigned u = fkey(dd);
          unsigned ix = (unsigned)m;
          bool beat = (u > rv[KK-1]) || (u == rv[KK-1] && ix < ri[KK-1]);
          if (u >= T && beat){
            unsigned pv = u, pi = ix;
            #pragma unroll
            for (int p = 0; p < KK; ++p){
              bool keep2 = (rv[p] > pv) || (rv[p] == pv && ri[p] < pi);
              unsigned nv = keep2 ? rv[p] : pv;
              unsigned ni = keep2 ? ri[p] : pi;
              pv = keep2 ? pv : rv[p];
              pi = keep2 ? pi : ri[p];
              rv[p] = nv; ri[p] = ni;
            }
          }
        }
      }
    }
    for (int q = 0; q < KK; ++q){
      unsigned bv = rv[0], bi = ri[0];
      #pragma unroll
      for (int s = 1; s < 64; s <<= 1){
        unsigned ov = __shfl_xor(bv, s);
        unsigned oi = __shfl_xor(bi, s);
        bool take = (ov > bv) || (ov == bv && oi < bi);
        bv = take ? ov : bv;
        bi = take ? oi : bi;
      }
      if (rv[0] == bv && ri[0] == bi){
        #pragma unroll
        for (int p = 0; p < KK-1; ++p){ rv[p] = rv[p+1]; ri[p] = ri[p+1]; }
        rv[KK-1] = 0u; ri[KK-1] = 0xFFFFFFFFu;
      }
      if (lane == 0) orow[q] = (int)bi;
    }
  }
}

// ---- U = W[:, :64] * x ; T = (W[:,64:] - W[:, :64]) * x  (per point, point-major out)
__global__ void ut_kernel(const float* __restrict__ xcat, int ofs, const float* __restrict__ W,
                          float* __restrict__ U, float* __restrict__ T){
  __shared__ float Wl[64*129];
  int tid = threadIdx.x;
  for (int i = tid; i < 64*128; i += 256){
    int o = i >> 7, c = i & 127;
    Wl[o*129 + c] = W[i];
  }
  __syncthreads();
  int g = tid >> 6, lane = tid & 63;
  int p = blockIdx.x*4 + g;
  float xv = xcat[(size_t)p*192 + ofs + lane];
  const float* wr = Wl + lane*129;
  float u = 0.f, t = 0.f;
  for (int c = 0; c < 64; ++c){
    float xc = __shfl(xv, c);
    float wa = wr[c], wb = wr[64+c];
    u += wa*xc;
    t += (wb - wa)*xc;
  }
  U[(size_t)p*64 + lane] = u;
  T[(size_t)p*64 + lane] = t;
}

// ---- ONE gather pass: v = U[j]+T[n] over k -> per-channel partial sum/sumsq
// (deterministic slots) AND per-(point,ch) vmax/vmin (lrelu-monotone max trick).
__global__ void gather_kernel(const float* __restrict__ U, const float* __restrict__ T,
                              const int* __restrict__ idx,
                              float* __restrict__ psum, float* __restrict__ psumsq,
                              float* __restrict__ vmax, float* __restrict__ vmin){
  int tid = threadIdx.x;
  int g = tid >> 6, lane = tid & 63;
  int p0 = blockIdx.x*64 + g*16;
  float s = 0.f, ss = 0.f;
  for (int pi = 0; pi < 16; ++pi){
    int p = p0 + pi;
    int base = (p >> 12) << 12;
    float t = T[(size_t)p*64 + lane];
    const int* ir = idx + (size_t)p*KK;
    float mx = -INFINITY, mn = INFINITY;
    for (int k = 0; k < KK; ++k){
      int j = ir[k];
      float v = U[(size_t)(base + j)*64 + lane] + t;
      s += v; ss += v*v;
      mx = fmaxf(mx, v); mn = fminf(mn, v);
    }
    vmax[(size_t)p*64 + lane] = mx;
    vmin[(size_t)p*64 + lane] = mn;
  }
  __shared__ float rs[4][64], rss[4][64];
  rs[g][lane] = s; rss[g][lane] = ss;
  __syncthreads();
  if (g == 0){
    s  = rs[0][lane]+rs[1][lane]+rs[2][lane]+rs[3][lane];
    ss = rss[0][lane]+rss[1][lane]+rss[2][lane]+rss[3][lane];
    psum[(size_t)blockIdx.x*64 + lane] = s;
    psumsq[(size_t)blockIdx.x*64 + lane] = ss;
  }
}

// ---- elementwise: x_out[p,o] = lrelu(s*(s>=0?vmax:vmin)+t) -> xcat[:, ofs:ofs+64]
__global__ void gapply_kernel(const float* __restrict__ vmax, const float* __restrict__ vmin,
                              const float* __restrict__ scale, const float* __restrict__ shift,
                              float* __restrict__ xcat, int ofs){
  int i = blockIdx.x*256 + threadIdx.x;
  int p = i >> 6, o = i & 63;
  float s = scale[o];
  float v = (s >= 0.f) ? vmax[i] : vmin[i];
  xcat[(size_t)p*192 + ofs + o] = lrelu(s*v + shift[o]);
}

// ---- point-major matmul, 128p x 64o tile, 8x4 acc/thread (conv6/conv7), split staging.
__global__ void __launch_bounds__(256, 2)
mm_kernel(const float* __restrict__ in, int inStride, int inOfs,
          const float* __restrict__ W, int wStride,
          float* __restrict__ out, int outStride,
          const float* __restrict__ bias, int O, int I,
          const float* __restrict__ bnScale, const float* __restrict__ bnShift){
  __shared__ float As[64*AS_STRIDE + 64];
  __shared__ float Ws[64*WS_STRIDE + 64];
  int tid = threadIdx.x;
  int p0 = blockIdx.x*128, o0 = blockIdx.y*64;
  int psub = (tid >> 4)*8, osub = (tid & 15)*4;
  int cgrp = (tid & 15)*4;
  float acc[8][4] = {};
  for (int cc = 0; cc < I; cc += 64){
    float4 sc4 = make_float4(1.f,1.f,1.f,1.f), sh4 = make_float4(0.f,0.f,0.f,0.f);
    if (bnScale){
      sc4 = *(const float4*)(bnScale + cc + cgrp);
      sh4 = *(const float4*)(bnShift + cc + cgrp);
    }
    float4 vin[8], vw[4];
    #pragma unroll
    for (int j = 0; j < 8; ++j){
      int row = (tid + 256*j) >> 4;
      vin[j] = *(const float4*)(in + (size_t)(p0+row)*inStride + inOfs + cc + cgrp);
    }
    #pragma unroll
    for (int j = 0; j < 4; ++j){
      int row = (tid + 256*j) >> 4;
      vw[j] = *(const float4*)(W + (size_t)(o0+row)*wStride + cc + cgrp);
    }
    #pragma unroll
    for (int j = 0; j < 8; ++j){
      int row = (tid + 256*j) >> 4, c4 = cgrp;
      float4 v = vin[j];
      if (bnScale){
        v.x = lrelu(v.x*sc4.x + sh4.x); v.y = lrelu(v.y*sc4.y + sh4.y);
        v.z = lrelu(v.z*sc4.z + sh4.z); v.w = lrelu(v.w*sc4.w + sh4.w);
      }
      As[(c4+0)*AS_STRIDE+SKEW(c4+0)+row]=v.x; As[(c4+1)*AS_STRIDE+SKEW(c4+1)+row]=v.y;
      As[(c4+2)*AS_STRIDE+SKEW(c4+2)+row]=v.z; As[(c4+3)*AS_STRIDE+SKEW(c4+3)+row]=v.w;
    }
    #pragma unroll
    for (int j = 0; j < 4; ++j){
      int row = (tid + 256*j) >> 4, c4 = cgrp;
      float4 v = vw[j];
      Ws[(c4+0)*WS_STRIDE+SKEW(c4+0)+row]=v.x; Ws[(c4+1)*WS_STRIDE+SKEW(c4+1)+row]=v.y;
      Ws[(c4+2)*WS_STRIDE+SKEW(c4+2)+row]=v.z; Ws[(c4+3)*WS_STRIDE+SKEW(c4+3)+row]=v.w;
    }
    __syncthreads();
    for (int c = 0; c < 64; ++c){
      const float* arow = &As[c*AS_STRIDE + SKEW(c)];
      const float* brow = &Ws[c*WS_STRIDE + SKEW(c)];
      float4 a0 = *(const float4*)&arow[psub];
      float4 a1 = *(const float4*)&arow[psub + 4];
      float4 bb = *(const float4*)&brow[osub];
      float av[8] = {a0.x,a0.y,a0.z,a0.w,a1.x,a1.y,a1.z,a1.w};
      float bv[4] = {bb.x,bb.y,bb.z,bb.w};
      #pragma unroll
      for (int i = 0; i < 8; ++i)
        #pragma unroll
        for (int j = 0; j < 4; ++j)
          acc[i][j] += av[i]*bv[j];
    }
    __syncthreads();
  }
  int bIdx = p0 >> 12;
  float bb0=0.f, bb1=0.f, bb2=0.f, bb3=0.f;
  if (bias){
    bb0 = bias[bIdx*O + o0 + osub + 0];
    bb1 = bias[bIdx*O + o0 + osub + 1];
    bb2 = bias[bIdx*O + o0 + osub + 2];
    bb3 = bias[bIdx*O + o0 + osub + 3];
  }
  #pragma unroll
  for (int i = 0; i < 8; ++i){
    float4 w;
    w.x = acc[i][0]+bb0; w.y = acc[i][1]+bb1; w.z = acc[i][2]+bb2; w.w = acc[i][3]+bb3;
    *(float4*)(out + (size_t)(p0+psub+i)*outStride + o0 + osub) = w;
  }
}

// ---- point-major matmul, 128p x 128o tile, 8x8 acc/thread, split fragments,
// split staging (conv5).
__global__ void __launch_bounds__(256, 2)
mm128_kernel(const float* __restrict__ in, int inStride, int inOfs,
             const float* __restrict__ W, int wStride,
             float* __restrict__ out, int outStride,
             const float* __restrict__ bias, int O, int I,
             const float* __restrict__ bnScale, const float* __restrict__ bnShift){
  __shared__ float As[64*AS_STRIDE + 64];
  __shared__ float Ws[64*AS_STRIDE + 64];
  int tid = threadIdx.x;
  int p0 = blockIdx.x*128, o0 = blockIdx.y*128;
  int pA = (tid >> 4)*4, oB = (tid & 15)*4;
  int cgrp = (tid & 15)*4;
  float acc[8][8] = {};
  for (int cc = 0; cc < I; cc += 64){
    float4 sc4 = make_float4(1.f,1.f,1.f,1.f), sh4 = make_float4(0.f,0.f,0.f,0.f);
    if (bnScale){
      sc4 = *(const float4*)(bnScale + cc + cgrp);
      sh4 = *(const float4*)(bnShift + cc + cgrp);
    }
    float4 vin[8], vw[8];
    #pragma unroll
    for (int j = 0; j < 8; ++j){
      int row = (tid + 256*j) >> 4;
      vin[j] = *(const float4*)(in + (size_t)(p0+row)*inStride + inOfs + cc + cgrp);
      vw[j]  = *(const float4*)(W + (size_t)(o0+row)*wStride + cc + cgrp);
    }
    #pragma unroll
    for (int j = 0; j < 8; ++j){
      int row = (tid + 256*j) >> 4, c4 = cgrp;
      float4 v = vin[j];
      if (bnScale){
        v.x = lrelu(v.x*sc4.x + sh4.x); v.y = lrelu(v.y*sc4.y + sh4.y);
        v.z = lrelu(v.z*sc4.z + sh4.z); v.w = lrelu(v.w*sc4.w + sh4.w);
      }
      As[(c4+0)*AS_STRIDE+SKEW(c4+0)+row]=v.x; As[(c4+1)*AS_STRIDE+SKEW(c4+1)+row]=v.y;
      As[(c4+2)*AS_STRIDE+SKEW(c4+2)+row]=v.z; As[(c4+3)*AS_STRIDE+SKEW(c4+3)+row]=v.w;
      float4 w = vw[j];
      Ws[(c4+0)*AS_STRIDE+SKEW(c4+0)+row]=w.x; Ws[(c4+1)*AS_STRIDE+SKEW(c4+1)+row]=w.y;
      Ws[(c4+2)*AS_STRIDE+SKEW(c4+2)+row]=w.z; Ws[(c4+3)*AS_STRIDE+SKEW(c4+3)+row]=w.w;
    }
    __syncthreads();
    for (int c = 0; c < 64; ++c){
      const float* arow = &As[c*AS_STRIDE + SKEW(c)];
      const float* brow = &Ws[c*AS_STRIDE + SKEW(c)];
      float4 a0 = *(const float4*)&arow[pA];
      float4 a1 = *(const float4*)&arow[pA + 64];
      float4 b0 = *(const float4*)&brow[oB];
      float4 b1 = *(const float4*)&brow[oB + 64];
      float av[8] = {a0.x,a0.y,a0.z,a0.w,a1.x,a1.y,a1.z,a1.w};
      float bv[8] = {b0.x,b0.y,b0.z,b0.w,b1.x,b1.y,b1.z,b1.w};
      #pragma unroll
      for (int i = 0; i < 8; ++i)
        #pragma unroll
        for (int j = 0; j < 8; ++j)
          acc[i][j] += av[i]*bv[j];
    }
    __syncthreads();
  }
  int bIdx = p0 >> 12;
  float bb[8] = {0.f,0.f,0.f,0.f,0.f,0.f,0.f,0.f};
  if (bias){
    #pragma unroll
    for (int j = 0; j < 4; ++j){
      bb[j]   = bias[bIdx*O + o0 + oB + j];
      bb[4+j] = bias[bIdx*O + o0 + 64 + oB + j];
    }
  }
  #pragma unroll
  for (int h = 0; h < 2; ++h){
    #pragma unroll
    for (int i = 0; i < 4; ++i){
      int row = p0 + h*64 + pA + i;
      int ai = h*4 + i;
      float4 w0, w1;
      w0.x = acc[ai][0]+bb[0]; w0.y = acc[ai][1]+bb[1];
      w0.z = acc[ai][2]+bb[2]; w0.w = acc[ai][3]+bb[3];
      w1.x = acc[ai][4]+bb[4]; w1.y = acc[ai][5]+bb[5];
      w1.z = acc[ai][6]+bb[6]; w1.w = acc[ai][7]+bb[7];
      float* orow = out + (size_t)row*outStride + o0;
      *(float4*)(orow + oB) = w0;
      *(float4*)(orow + 64 + oB) = w1;
    }
  }
}

// ---- conv4 FUSED with stats: computes the 128x128 r4 tile in registers, then
// reduces in-block to per-channel sum/sumsq partials + per-(tile,ch) max/min.
// r4 is NEVER materialized (saves its 33.5 MB write + 33.5 MB stats re-read).
__global__ void __launch_bounds__(256, 2)
conv4stats_kernel(const float* __restrict__ xcat, const float* __restrict__ W4,
                  float* __restrict__ psum, float* __restrict__ psumsq,
                  float* __restrict__ pmax, float* __restrict__ pmin){
  __shared__ float As[64*AS_STRIDE + 64];
  __shared__ float Ws[64*AS_STRIDE + 64];
  int tid = threadIdx.x;
  int p0 = blockIdx.x*128, o0 = blockIdx.y*128;
  int pA = (tid >> 4)*4, oB = (tid & 15)*4;
  int cgrp = (tid & 15)*4;
  float4 vin[8], vw[8];
  #pragma unroll
  for (int j = 0; j < 8; ++j){
    int row = (tid + 256*j) >> 4;
    vin[j] = *(const float4*)(xcat + (size_t)(p0+row)*192 + 128 + cgrp);
    vw[j]  = *(const float4*)(W4 + (size_t)(o0+row)*64 + cgrp);
  }
  #pragma unroll
  for (int j = 0; j < 8; ++j){
    int row = (tid + 256*j) >> 4, c4 = cgrp;
    float4 v = vin[j];
    As[(c4+0)*AS_STRIDE+SKEW(c4+0)+row]=v.x; As[(c4+1)*AS_STRIDE+SKEW(c4+1)+row]=v.y;
    As[(c4+2)*AS_STRIDE+SKEW(c4+2)+row]=v.z; As[(c4+3)*AS_STRIDE+SKEW(c4+3)+row]=v.w;
    float4 w = vw[j];
    Ws[(c4+0)*AS_STRIDE+SKEW(c4+0)+row]=w.x; Ws[(c4+1)*AS_STRIDE+SKEW(c4+1)+row]=w.y;
    Ws[(c4+2)*AS_STRIDE+SKEW(c4+2)+row]=w.z; Ws[(c4+3)*AS_STRIDE+SKEW(c4+3)+row]=w.w;
  }
  __syncthreads();
  float acc[8][8] = {};
  for (int c = 0; c < 64; ++c){
    const float* arow = &As[c*AS_STRIDE + SKEW(c)];
    const float* brow = &Ws[c*AS_STRIDE + SKEW(c)];
    float4 a0 = *(const float4*)&arow[pA];
    float4 a1 = *(const float4*)&arow[pA + 64];
    float4 b0 = *(const float4*)&brow[oB];
    float4 b1 = *(const float4*)&brow[oB + 64];
    float av[8] = {a0.x,a0.y,a0.z,a0.w,a1.x,a1.y,a1.z,a1.w};
    float bv[8] = {b0.x,b0.y,b0.z,b0.w,b1.x,b1.y,b1.z,b1.w};
    #pragma unroll
    for (int i = 0; i < 8; ++i)
      #pragma unroll
      for (int j = 0; j < 8; ++j)
        acc[i][j] += av[i]*bv[j];
  }
  // per-thread column partials over its 8 rows (fixed order i=0..7)
  float cs[8], cq[8], cmx[8], cmn[8];
  #pragma unroll
  for (int j = 0; j < 8; ++j){
    float s = 0.f, q = 0.f, mx = -INFINITY, mn = INFINITY;
    #pragma unroll
    for (int i = 0; i < 8; ++i){
      float v = acc[i][j];
      s += v; q += v*v; mx = fmaxf(mx, v); mn = fminf(mn, v);
    }
    cs[j]=s; cq[j]=q; cmx[j]=mx; cmn[j]=mn;
  }
  __syncthreads();   // done reading As/Ws; reuse as scratch
  int r = tid >> 4;
  #pragma unroll
  for (int j = 0; j < 8; ++j){
    int col = (j < 4) ? (oB + j) : (64 + oB + (j-4));
    As[r*128 + col]        = cs[j];
    As[2048 + r*128 + col] = cq[j];
    Ws[r*128 + col]        = cmx[j];
    Ws[2048 + r*128 + col] = cmn[j];
  }
  __syncthreads();
  if (tid < 128){
    float ts = 0.f, tq = 0.f, tm = -INFINITY, tn = INFINITY;
    for (int rr = 0; rr < 16; ++rr){
      ts += As[rr*128 + tid];
      tq += As[2048 + rr*128 + tid];
      tm = fmaxf(tm, Ws[rr*128 + tid]);
      tn = fminf(tn, Ws[2048 + rr*128 + tid]);
    }
    size_t slot = (size_t)blockIdx.x*512 + o0 + tid;
    psum[slot] = ts; psumsq[slot] = tq; pmax[slot] = tm; pmin[slot] = tn;
  }
}

// lrelu(s*v+t) monotone in v: use max if s>=0 else min  (32 tiles per batch)
__global__ void x6v_kernel(const float* __restrict__ pmax, const float* __restrict__ pmin,
                           const float* __restrict__ scale, const float* __restrict__ shift,
                           float* __restrict__ x6v){
  int t = blockIdx.x*256 + threadIdx.x;
  int b = t >> 9, o = t & 511;
  float mx = -INFINITY, mn = INFINITY;
  for (int pt = b*32; pt < b*32+32; ++pt){
    mx = fmaxf(mx, pmax[(size_t)pt*512 + o]);
    mn = fminf(mn, pmin[(size_t)pt*512 + o]);
  }
  float s = scale[o];
  float v = (s >= 0.f) ? mx : mn;
  x6v[t] = lrelu(s*v + shift[o]);
}

// bias5[b,o] = sum_c W5[o, 192+c] * x6v[b,c]   (the broadcast part of the concat)
__global__ void bias5_kernel(const float* __restrict__ W5, const float* __restrict__ x6v,
                             float* __restrict__ b5){
  __shared__ float xl[512];
  int tid = threadIdx.x;
  int t = blockIdx.x*256 + tid;
  int b = t >> 9, o = t & 511;
  for (int i = tid; i < 512; i += 256) xl[i] = x6v[(b<<9) + i];
  __syncthreads();
  const float* wr = W5 + (size_t)o*704 + 192;
  float acc = 0.f;
  for (int c = 0; c < 512; ++c) acc += wr[c]*xl[c];
  b5[t] = acc;
}

// ---- conv8 (128->2) + bias over raw r7 with BN7+lrelu applied inline
__global__ void conv8_kernel(const float* __restrict__ r7, const float* __restrict__ W8,
                             const float* __restrict__ bias8,
                             const float* __restrict__ scale, const float* __restrict__ shift,
                             float* __restrict__ out){
  __shared__ float Wl[256];
  __shared__ float scl[128], shl[128];
  int tid = threadIdx.x;
  Wl[tid] = W8[tid];
  if (tid < 128){ scl[tid] = scale[tid]; shl[tid] = shift[tid]; }
  __syncthreads();
  int p = blockIdx.x*256 + tid;
  int b = p >> 12, n = p & 4095;
  const float4* row = (const float4*)(r7 + (size_t)p*128);
  float a0 = 0.f, a1 = 0.f;
  #pragma unroll
  for (int i = 0; i < 32; ++i){
    float4 v = row[i];
    v.x = lrelu(v.x*scl[i*4+0] + shl[i*4+0]);
    v.y = lrelu(v.y*scl[i*4+1] + shl[i*4+1]);
    v.z = lrelu(v.z*scl[i*4+2] + shl[i*4+2]);
    v.w = lrelu(v.w*scl[i*4+3] + shl[i*4+3]);
    a0 += v.x*Wl[i*4] + v.y*Wl[i*4+1] + v.z*Wl[i*4+2] + v.w*Wl[i*4+3];
    a1 += v.x*Wl[128+i*4] + v.y*Wl[128+i*4+1] + v.z*Wl[128+i*4+2] + v.w*Wl[128+i*4+3];
  }
  out[(size_t)(b*2+0)*NN + n] = a0 + bias8[0];
  out[(size_t)(b*2+1)*NN + n] = a1 + bias8[1];
}

extern "C" void kernel_launch(void* const* d_in, const int* in_sizes, int n_in,
                              void* d_out, int out_size, void* d_ws, size_t ws_size,
                              hipStream_t stream){
  const float* x     = (const float*)d_in[0];
  const float* W1    = (const float*)d_in[1];
  const float* W2    = (const float*)d_in[2];
  const float* W3    = (const float*)d_in[3];
  const float* W4    = (const float*)d_in[4];
  const float* W5    = (const float*)d_in[5];
  const float* W6    = (const float*)d_in[6];
  const float* W7    = (const float*)d_in[7];
  const float* W8    = (const float*)d_in[8];
  const float* bias8 = (const float*)d_in[9];
  const float* gamma[8]; const float* beta[8];
  for (int i = 1; i <= 7; ++i){
    gamma[i] = (const float*)d_in[10 + 2*(i-1)];
    beta[i]  = (const float*)d_in[11 + 2*(i-1)];
  }
  float* out = (float*)d_out;

  float* ws = (float*)d_ws;
  size_t off = 0;
  float* xcat  = ws + off; off += (size_t)NPT*192;   // x1|x2|x3 packed, stride 192
  float* U     = ws + off; off += (size_t)NPT*64;
  float* T     = ws + off; off += (size_t)NPT*64;
  float* xx    = ws + off; off += NPT;
  int*   idx   = (int*)(ws + off); off += (size_t)NPT*KK;
  float* psum  = ws + off; off += 128*512;
  float* psumsq= ws + off; off += 128*512;
  float* pmax  = ws + off; off += 128*512;
  float* pmin  = ws + off; off += 128*512;
  float* scale = ws + off; off += 512;
  float* shift = ws + off; off += 512;
  float* x6v   = ws + off; off += 2048;
  float* b5    = ws + off; off += 2048;
  float* big   = ws + off;   // time-shared: gmax (knn) / vmax|vmin (gather) / r5|r6|r7
  unsigned* gmaxB = (unsigned*)big;                 // NPT*512 u32 = 32MB (knn only)
  float* vmaxB = big;                               // NPT*64, live only between knn rounds
  float* vminB = big + (size_t)NPT*64;
  float* r5    = big;
  float* r6    = big + (size_t)NPT*512;
  float* r7    = big + (size_t)NPT*512 + (size_t)NPT*256;

  // ---- stage 1: conv1 + BN(train stats) + lrelu -> x1 (xcat[:,0:64])
  conv1_kernel<<<NPT/4, 256, 0, stream>>>(x, W1, xcat);
  stats_pm_kernel<<<dim3(1,64), 256, 0, stream>>>(xcat, 192, 0, psum, psumsq, 64);
  bn_finalize_kernel<<<1, 64, 0, stream>>>(psum, psumsq, 64, gamma[1], beta[1], scale, shift, 1.f/16384.f, 64);
  apply_bn_kernel<<<NPT*64/256, 256, 0, stream>>>(xcat, 192, 0, 6, scale, shift);

  // ---- knn on x1: gmax (no dist matrix) + recompute-filtered exact top-20
  xx_kernel<<<NPT/256, 256, 0, stream>>>(xcat, 192, 0, xx);
  gmax_kernel<<<dim3(32,32,BB), 256, 0, stream>>>(xcat, 0, xx, gmaxB);
  topk_kernel<<<dim3(NN/4,1,BB), 256, 0, stream>>>(xcat, 0, xx, gmaxB, idx);

  // ---- stage 2: edge-conv (W2): single gather pass (stats + vmax/vmin), then elementwise
  ut_kernel<<<NPT/4, 256, 0, stream>>>(xcat, 0, W2, U, T);
  gather_kernel<<<256, 256, 0, stream>>>(U, T, idx, psum, psumsq, vmaxB, vminB);
  bn_finalize_kernel<<<1, 64, 0, stream>>>(psum, psumsq, 256, gamma[2], beta[2], scale, shift, 1.f/327680.f, 64);
  gapply_kernel<<<NPT*64/256, 256, 0, stream>>>(vmaxB, vminB, scale, shift, xcat, 64);

  // ---- knn on x2
  xx_kernel<<<NPT/256, 256, 0, stream>>>(xcat, 192, 64, xx);
  gmax_kernel<<<dim3(32,32,BB), 256, 0, stream>>>(xcat, 64, xx, gmaxB);
  topk_kernel<<<dim3(NN/4,1,BB), 256, 0, stream>>>(xcat, 64, xx, gmaxB, idx);

  // ---- stage 3: edge-conv (W3) -> x3
  ut_kernel<<<NPT/4, 256, 0, stream>>>(xcat, 64, W3, U, T);
  gather_kernel<<<256, 256, 0, stream>>>(U, T, idx, psum, psumsq, vmaxB, vminB);
  bn_finalize_kernel<<<1, 64, 0, stream>>>(psum, psumsq, 256, gamma[3], beta[3], scale, shift, 1.f/327680.f, 64);
  gapply_kernel<<<NPT*64/256, 256, 0, stream>>>(vmaxB, vminB, scale, shift, xcat, 128);

  // ---- stage 4: conv4 fused with stats (r4 never materialized)
  conv4stats_kernel<<<dim3(NPT/128, 4), 256, 0, stream>>>(xcat, W4, psum, psumsq, pmax, pmin);
  bn_finalize_kernel<<<1, 512, 0, stream>>>(psum, psumsq, 128, gamma[4], beta[4], scale, shift, 1.f/16384.f, 512);
  x6v_kernel<<<8, 256, 0, stream>>>(pmax, pmin, scale, shift, x6v);
  bias5_kernel<<<8, 256, 0, stream>>>(W5, x6v, b5);

  // ---- stage 5: conv5 (704->512) = mm128 over packed 192 + bias5; r5 stays RAW
  mm128_kernel<<<dim3(NPT/128, 4), 256, 0, stream>>>(xcat, 192, 0, W5, 704, r5, 512, b5, 512, 192, nullptr, nullptr);
  stats_pm_kernel<<<dim3(8,64), 256, 0, stream>>>(r5, 512, 0, psum, psumsq, 512);
  bn_finalize_kernel<<<1, 512, 0, stream>>>(psum, psumsq, 64, gamma[5], beta[5], scale, shift, 1.f/16384.f, 512);

  // ---- stage 6: conv6 (512->256), BN5+lrelu on load; r6 stays RAW.
  // 64-out tiles (mm_kernel) -> 512 blocks = 2 blocks/CU.
  mm_kernel<<<dim3(NPT/128, 4), 256, 0, stream>>>(r5, 512, 0, W6, 512, r6, 256, nullptr, 256, 512, scale, shift);
  stats_pm_kernel<<<dim3(4,64), 256, 0, stream>>>(r6, 256, 0, psum, psumsq, 256);
  bn_finalize_kernel<<<1, 256, 0, stream>>>(psum, psumsq, 64, gamma[6], beta[6], scale, shift, 1.f/16384.f, 256);

  // ---- stage 7: conv7 (256->128), BN6+lrelu on load; r7 stays RAW
  mm_kernel<<<dim3(NPT/128, 2), 256, 0, stream>>>(r6, 256, 0, W7, 256, r7, 128, nullptr, 128, 256, scale, shift);
  stats_pm_kernel<<<dim3(2,64), 256, 0, stream>>>(r7, 128, 0, psum, psumsq, 128);
  bn_finalize_kernel<<<1, 128, 0, stream>>>(psum, psumsq, 64, gamma[7], beta[7], scale, shift, 1.f/16384.f, 128);

  // ---- stage 8: conv8 (128->2) + bias, BN7+lrelu applied inline
  conv8_kernel<<<NPT/256, 256, 0, stream>>>(r7, W8, bias8, scale, shift, out);
}

// Round 9
// 1096.074 us; speedup vs baseline: 1.7037x; 1.7037x over previous
//
#include <hip/hip_runtime.h>
#include <math.h>

#define NN 4096
#define BB 4
#define NPT (NN*BB)
#define KK 20
#define EPSB 1e-5f

#define AS_STRIDE 132   // 128-point c-row, padded
#define WS_STRIDE 68    // 64-col c-row, padded
// Non-wrapping per-channel skew: staging writes 2-way (free), reads clean,
// all offsets multiples of 4 floats so float4 reads stay 16B-aligned.
#define SKEW(c) ((((((c)>>2)&7))<<2) + (((c)>>5)*28))

__device__ __forceinline__ float lrelu(float x){ return x >= 0.f ? x : 0.2f*x; }

// monotone float->uint key: order(key) == order(float)
__device__ __forceinline__ unsigned fkey(float x){
  unsigned u = __float_as_uint(x);
  return u ^ (unsigned)(((int)u >> 31) | 0x80000000);
}

// ---- stage 1: conv1 (3->64), writes raw into xcat[:, 0:64] (point-major, row stride 192)
__global__ void conv1_kernel(const float* __restrict__ x, const float* __restrict__ W1,
                             float* __restrict__ xcat){
  __shared__ float Wl[192];
  int tid = threadIdx.x;
  if (tid < 192) Wl[tid] = W1[tid];
  __syncthreads();
  int p = blockIdx.x*4 + (tid >> 6);
  int o = tid & 63;
  int b = p >> 12, n = p & 4095;
  const float* xb = x + (size_t)b*3*NN + n;
  float acc = Wl[o*3+0]*xb[0] + Wl[o*3+1]*xb[NN] + Wl[o*3+2]*xb[2*NN];
  xcat[(size_t)p*192 + o] = acc;
}

// ---- per-channel partial stats for point-major (NPT, C) buffer; deterministic slots
__global__ void stats_pm_kernel(const float* __restrict__ buf, int stride, int ofs,
                                float* __restrict__ psum, float* __restrict__ psumsq, int C){
  int tid = threadIdx.x;
  int lane = tid & 63, g = tid >> 6;
  int o = blockIdx.x*64 + lane;
  int p0 = blockIdx.y*256 + g*64;
  float s = 0.f, ss = 0.f;
  for (int i = 0; i < 64; ++i){
    float v = buf[(size_t)(p0+i)*stride + ofs + o];
    s += v; ss += v*v;
  }
  __shared__ float rs[4][64], rss[4][64];
  rs[g][lane] = s; rss[g][lane] = ss;
  __syncthreads();
  if (g == 0){
    s  = rs[0][lane]+rs[1][lane]+rs[2][lane]+rs[3][lane];
    ss = rss[0][lane]+rss[1][lane]+rss[2][lane]+rss[3][lane];
    psum[(size_t)blockIdx.y*C + o] = s;
    psumsq[(size_t)blockIdx.y*C + o] = ss;
  }
}

// deterministic finalize: serial sum over nparts partials per channel
__global__ void bn_finalize_kernel(const float* __restrict__ psum, const float* __restrict__ psumsq,
                                   int nparts,
                                   const float* __restrict__ gamma, const float* __restrict__ beta,
                                   float* __restrict__ scale, float* __restrict__ shift,
                                   float invcnt, int C){
  int o = threadIdx.x + blockIdx.x*blockDim.x;
  if (o >= C) return;
  float s = 0.f, ss = 0.f;
  for (int i = 0; i < nparts; ++i){
    s  += psum[(size_t)i*C + o];
    ss += psumsq[(size_t)i*C + o];
  }
  float m = s*invcnt;
  float v = ss*invcnt - m*m;
  v = fmaxf(v, 0.f);
  float sc = gamma[o] * rsqrtf(v + EPSB);
  scale[o] = sc;
  shift[o] = beta[o] - m*sc;
}

__global__ void apply_bn_kernel(float* __restrict__ buf, int stride, int ofs, int log2C,
                                const float* __restrict__ scale, const float* __restrict__ shift){
  int i = blockIdx.x*256 + threadIdx.x;
  int o = i & ((1<<log2C)-1);
  int p = i >> log2C;
  size_t a = (size_t)p*stride + ofs + o;
  float e = buf[a]*scale[o] + shift[o];
  buf[a] = lrelu(e);
}

// ---- ||x||^2 per point (64 features)
__global__ void xx_kernel(const float* __restrict__ xcat, int stride, int ofs,
                          float* __restrict__ xx){
  int p = blockIdx.x*256 + threadIdx.x;
  const float4* r = (const float4*)(xcat + (size_t)p*stride + ofs);
  float s = 0.f;
  #pragma unroll
  for (int i = 0; i < 16; ++i){ float4 v = r[i]; s += v.x*v.x + v.y*v.y + v.z*v.z + v.w*v.w; }
  xx[p] = s;
}

// ---- dist: TRIANGULAR 128n x 128m tiles (by<=bx) + mirror write. Bit-identical
// values to the verified kernel. ALSO writes per-(row,group-of-8) key-maxima
// (gmax, u32 keys) for the filtered topk. Group gid: cols {cb..cb+3,
// cb+64..cb+67}, cb = (gid>>4)*128 + (gid&15)*4. Each (row,gid) written once.
__global__ void __launch_bounds__(256, 2)
dist_kernel(const float* __restrict__ xcat, int ofs,
            const float* __restrict__ xx, float* __restrict__ dist,
            unsigned* __restrict__ gmaxp, int b){
  int bx = blockIdx.x, by = blockIdx.y;
  if (by > bx) return;                 // lower triangle filled by mirror
  __shared__ float As[64*AS_STRIDE + 64];
  __shared__ float Bs[64*AS_STRIDE + 64];
  int tid = threadIdx.x;
  int n0 = by*128, m0 = bx*128;        // row tile <= col tile
  const float* base = xcat + (size_t)b*NN*192 + ofs;
  int cgrp = (tid & 15)*4;
  float4 vin[8], vw[8];
  #pragma unroll
  for (int j = 0; j < 8; ++j){
    int row = (tid + 256*j) >> 4;
    vin[j] = *(const float4*)(base + (size_t)(n0+row)*192 + cgrp);
    vw[j]  = *(const float4*)(base + (size_t)(m0+row)*192 + cgrp);
  }
  #pragma unroll
  for (int j = 0; j < 8; ++j){
    int row = (tid + 256*j) >> 4, c4 = cgrp;
    float4 v = vin[j];
    As[(c4+0)*AS_STRIDE+SKEW(c4+0)+row]=v.x; As[(c4+1)*AS_STRIDE+SKEW(c4+1)+row]=v.y;
    As[(c4+2)*AS_STRIDE+SKEW(c4+2)+row]=v.z; As[(c4+3)*AS_STRIDE+SKEW(c4+3)+row]=v.w;
    float4 w = vw[j];
    Bs[(c4+0)*AS_STRIDE+SKEW(c4+0)+row]=w.x; Bs[(c4+1)*AS_STRIDE+SKEW(c4+1)+row]=w.y;
    Bs[(c4+2)*AS_STRIDE+SKEW(c4+2)+row]=w.z; Bs[(c4+3)*AS_STRIDE+SKEW(c4+3)+row]=w.w;
  }
  __syncthreads();
  int pA = (tid >> 4)*4, oB = (tid & 15)*4;
  float acc[8][8] = {};   // i: 0-3 rows pA+i, 4-7 rows pA+64+(i-4); j likewise cols
  for (int c = 0; c < 64; ++c){
    const float* arow = &As[c*AS_STRIDE + SKEW(c)];
    const float* brow = &Bs[c*AS_STRIDE + SKEW(c)];
    float4 a0 = *(const float4*)&arow[pA];
    float4 a1 = *(const float4*)&arow[pA + 64];
    float4 b0 = *(const float4*)&brow[oB];
    float4 b1 = *(const float4*)&brow[oB + 64];
    float av[8] = {a0.x,a0.y,a0.z,a0.w,a1.x,a1.y,a1.z,a1.w};
    float bv[8] = {b0.x,b0.y,b0.z,b0.w,b1.x,b1.y,b1.z,b1.w};
    #pragma unroll
    for (int i = 0; i < 8; ++i)
      #pragma unroll
      for (int j = 0; j < 8; ++j)
        acc[i][j] += av[i]*bv[j];
  }
  float xmv[8], xnv[8];
  #pragma unroll
  for (int j = 0; j < 4; ++j){
    xmv[j]   = xx[b*NN + m0 + oB + j];
    xmv[4+j] = xx[b*NN + m0 + 64 + oB + j];
    xnv[j]   = xx[b*NN + n0 + pA + j];
    xnv[4+j] = xx[b*NN + n0 + 64 + pA + j];
  }
  #pragma unroll
  for (int h = 0; h < 2; ++h){
    #pragma unroll
    for (int i = 0; i < 4; ++i){
      int row = n0 + h*64 + pA + i;
      float xn = xnv[h*4 + i];
      int ai = h*4 + i;
      float4 w0, w1;
      w0.x = 2.f*acc[ai][0] - xn - xmv[0]; w0.y = 2.f*acc[ai][1] - xn - xmv[1];
      w0.z = 2.f*acc[ai][2] - xn - xmv[2]; w0.w = 2.f*acc[ai][3] - xn - xmv[3];
      w1.x = 2.f*acc[ai][4] - xn - xmv[4]; w1.y = 2.f*acc[ai][5] - xn - xmv[5];
      w1.z = 2.f*acc[ai][6] - xn - xmv[6]; w1.w = 2.f*acc[ai][7] - xn - xmv[7];
      float* drow = dist + (size_t)row*NN + m0;
      *(float4*)(drow + oB) = w0;
      *(float4*)(drow + 64 + oB) = w1;
      unsigned gm = fkey(w0.x), t;
      t = fkey(w0.y); if (t > gm) gm = t;
      t = fkey(w0.z); if (t > gm) gm = t;
      t = fkey(w0.w); if (t > gm) gm = t;
      t = fkey(w1.x); if (t > gm) gm = t;
      t = fkey(w1.y); if (t > gm) gm = t;
      t = fkey(w1.z); if (t > gm) gm = t;
      t = fkey(w1.w); if (t > gm) gm = t;
      gmaxp[(size_t)row*512 + (bx<<4) + (oB>>2)] = gm;
    }
  }
  if (bx != by){
    // mirror: element (m,n) = ((2a - xx[m]) - xx[n]); float4 along contiguous n
    #pragma unroll
    for (int jh = 0; jh < 2; ++jh){
      #pragma unroll
      for (int jj = 0; jj < 4; ++jj){
        int j = jh*4 + jj;
        float xm = xmv[j];
        float4 lo, hi;
        lo.x = 2.f*acc[0][j] - xm - xnv[0];
        lo.y = 2.f*acc[1][j] - xm - xnv[1];
        lo.z = 2.f*acc[2][j] - xm - xnv[2];
        lo.w = 2.f*acc[3][j] - xm - xnv[3];
        hi.x = 2.f*acc[4][j] - xm - xnv[4];
        hi.y = 2.f*acc[5][j] - xm - xnv[5];
        hi.z = 2.f*acc[6][j] - xm - xnv[6];
        hi.w = 2.f*acc[7][j] - xm - xnv[7];
        int mrow = m0 + jh*64 + oB + jj;
        float* drow = dist + (size_t)mrow*NN + n0;
        *(float4*)(drow + pA) = lo;
        *(float4*)(drow + 64 + pA) = hi;
        unsigned gm = fkey(lo.x), t;
        t = fkey(lo.y); if (t > gm) gm = t;
        t = fkey(lo.z); if (t > gm) gm = t;
        t = fkey(lo.w); if (t > gm) gm = t;
        t = fkey(hi.x); if (t > gm) gm = t;
        t = fkey(hi.y); if (t > gm) gm = t;
        t = fkey(hi.z); if (t > gm) gm = t;
        t = fkey(hi.w); if (t > gm) gm = t;
        gmaxp[(size_t)mrow*512 + (by<<4) + (pA>>2)] = gm;
      }
    }
  }
}

// ---- topk v3b: group-max prefilter + exact selection. One wave per row.
// T = conservative threshold from a SHORTENED binary radix over the 512 group
// maxima: scan bits 31..16 only, with early exit once the passing-group count
// (20-need)+|act| <= 44. Any prefix-truncated T satisfies T <= T_exact <= v20
// (>=20 groups have gmax >= T), so the value-filter key>=T keeps every top-20
// value incl. ties -> selection stays exact. Candidates gathered to per-wave
// LDS; C<=64: 64-lane bitonic sort (value desc, index asc); C>64: exact
// fallback rescans dist directly (independent of the LDS buffer).
__global__ void __launch_bounds__(256)
topk_kernel(const float* __restrict__ dist, const unsigned* __restrict__ gmax,
            int* __restrict__ idxout){
  __shared__ unsigned lv[4][256], li[4][256];
  __shared__ unsigned lcnt[4];
  int wv = threadIdx.x >> 6, lane = threadIdx.x & 63;
  int n = blockIdx.x*4 + wv;
  const unsigned* grow = gmax + (size_t)n*512;
  unsigned g[8];
  #pragma unroll
  for (int j = 0; j < 8; ++j) g[j] = grow[j*64 + lane];
  if (lane == 0) lcnt[wv] = 0u;          // same-wave LDS ops are in-order
  unsigned prefix = 0u, act = 0xFFu; int need = KK; int tot = 512;
  for (int b = 31; b >= 16; --b){
    unsigned m = 0u;
    #pragma unroll
    for (int j = 0; j < 8; ++j) m |= ((g[j] >> b) & 1u) << j;
    unsigned c = (unsigned)__popc(m & act);
    #pragma unroll
    for (int s = 1; s < 64; s <<= 1) c += __shfl_xor(c, s);
    if ((int)c >= need){ act &= m; prefix |= (1u << b); tot = (int)c; }
    else { need -= (int)c; act &= ~m; tot -= (int)c; }
    if (KK - need + tot <= 44) break;    // few enough passing groups: stop
  }
  unsigned T = prefix;                    // conservative (<= exact 20th gmax)
  const float* drow = dist + (size_t)n*NN;
  #pragma unroll
  for (int j = 0; j < 8; ++j){
    if (g[j] >= T){
      int gid = j*64 + lane;
      int cbase = ((gid >> 4) << 7) + ((gid & 15) << 2);
      float4 v0 = *(const float4*)(drow + cbase);
      float4 v1 = *(const float4*)(drow + cbase + 64);
      unsigned k0=fkey(v0.x),k1=fkey(v0.y),k2=fkey(v0.z),k3=fkey(v0.w);
      unsigned k4=fkey(v1.x),k5=fkey(v1.y),k6=fkey(v1.z),k7=fkey(v1.w);
      int q = (k0>=T)+(k1>=T)+(k2>=T)+(k3>=T)+(k4>=T)+(k5>=T)+(k6>=T)+(k7>=T);
      unsigned pos = atomicAdd(&lcnt[wv], (unsigned)q);
      #define PUTC(kx,cofs) if (kx >= T){ if (pos < 256u){ lv[wv][pos]=kx; li[wv][pos]=(unsigned)(cbase+(cofs)); } pos++; }
      PUTC(k0,0) PUTC(k1,1) PUTC(k2,2) PUTC(k3,3)
      PUTC(k4,64) PUTC(k5,65) PUTC(k6,66) PUTC(k7,67)
      #undef PUTC
    }
  }
  unsigned C = lcnt[wv];                  // all wave atomics precede this read
  int* orow = idxout + (size_t)n*KK;
  if (C <= 64u){
    unsigned kv = 0u, ki = 0xFFFFFFFFu;   // dummy key 0 = -inf, never a real dist
    if (lane < (int)C){ kv = lv[wv][lane]; ki = li[wv][lane]; }
    #pragma unroll
    for (int k = 2; k <= 64; k <<= 1){
      #pragma unroll
      for (int j2 = k >> 1; j2 > 0; j2 >>= 1){
        unsigned ov = __shfl_xor(kv, j2);
        unsigned oi = __shfl_xor(ki, j2);
        bool iLower = ((lane & j2) == 0);
        bool dirDesc = ((lane & k) == 0);
        bool mineGr = (kv > ov) || (kv == ov && ki < oi);
        bool keep = dirDesc ? (iLower ? mineGr : !mineGr)
                            : (iLower ? !mineGr : mineGr);
        kv = keep ? kv : ov;
        ki = keep ? ki : oi;
      }
    }
    if (lane < KK) orow[lane] = (int)ki;
  } else {
    // rare exact fallback: rescan qualifying groups, per-lane reg top-20 + merge
    unsigned rv[KK], ri[KK];
    #pragma unroll
    for (int q = 0; q < KK; ++q){ rv[q]=0u; ri[q]=0xFFFFFFFFu; }
    #pragma unroll
    for (int j = 0; j < 8; ++j){
      if (g[j] >= T){
        int gid = j*64 + lane;
        int cbase = ((gid >> 4) << 7) + ((gid & 15) << 2);
        float4 v0 = *(const float4*)(drow + cbase);
        float4 v1 = *(const float4*)(drow + cbase + 64);
        float f0[8] = {v0.x,v0.y,v0.z,v0.w,v1.x,v1.y,v1.z,v1.w};
        #pragma unroll
        for (int t = 0; t < 8; ++t){
          unsigned u = fkey(f0[t]);
          unsigned ix = (unsigned)(cbase + ((t < 4) ? t : (60 + t)));
          bool beat = (u > rv[KK-1]) || (u == rv[KK-1] && ix < ri[KK-1]);
          if (u >= T && beat){
            unsigned pv = u, pi = ix;
            #pragma unroll
            for (int p = 0; p < KK; ++p){
              bool keep2 = (rv[p] > pv) || (rv[p] == pv && ri[p] < pi);
              unsigned nv = keep2 ? rv[p] : pv;
              unsigned ni = keep2 ? ri[p] : pi;
              pv = keep2 ? pv : rv[p];
              pi = keep2 ? pi : ri[p];
              rv[p] = nv; ri[p] = ni;
            }
          }
        }
      }
    }
    for (int q = 0; q < KK; ++q){
      unsigned bv = rv[0], bi = ri[0];
      #pragma unroll
      for (int s = 1; s < 64; s <<= 1){
        unsigned ov = __shfl_xor(bv, s);
        unsigned oi = __shfl_xor(bi, s);
        bool take = (ov > bv) || (ov == bv && oi < bi);
        bv = take ? ov : bv;
        bi = take ? oi : bi;
      }
      if (rv[0] == bv && ri[0] == bi){
        #pragma unroll
        for (int p = 0; p < KK-1; ++p){ rv[p] = rv[p+1]; ri[p] = ri[p+1]; }
        rv[KK-1] = 0u; ri[KK-1] = 0xFFFFFFFFu;
      }
      if (lane == 0) orow[q] = (int)bi;
    }
  }
}

// ---- U = W[:, :64] * x ; T = (W[:,64:] - W[:, :64]) * x  (per point, point-major out)
__global__ void ut_kernel(const float* __restrict__ xcat, int ofs, const float* __restrict__ W,
                          float* __restrict__ U, float* __restrict__ T){
  __shared__ float Wl[64*129];
  int tid = threadIdx.x;
  for (int i = tid; i < 64*128; i += 256){
    int o = i >> 7, c = i & 127;
    Wl[o*129 + c] = W[i];
  }
  __syncthreads();
  int g = tid >> 6, lane = tid & 63;
  int p = blockIdx.x*4 + g;
  float xv = xcat[(size_t)p*192 + ofs + lane];
  const float* wr = Wl + lane*129;
  float u = 0.f, t = 0.f;
  for (int c = 0; c < 64; ++c){
    float xc = __shfl(xv, c);
    float wa = wr[c], wb = wr[64+c];
    u += wa*xc;
    t += (wb - wa)*xc;
  }
  U[(size_t)p*64 + lane] = u;
  T[(size_t)p*64 + lane] = t;
}

// ---- ONE gather pass: v = U[j]+T[n] over k -> per-channel partial sum/sumsq
// (deterministic slots) AND per-(point,ch) vmax/vmin (lrelu-monotone max trick).
__global__ void gather_kernel(const float* __restrict__ U, const float* __restrict__ T,
                              const int* __restrict__ idx,
                              float* __restrict__ psum, float* __restrict__ psumsq,
                              float* __restrict__ vmax, float* __restrict__ vmin){
  int tid = threadIdx.x;
  int g = tid >> 6, lane = tid & 63;
  int p0 = blockIdx.x*64 + g*16;
  float s = 0.f, ss = 0.f;
  for (int pi = 0; pi < 16; ++pi){
    int p = p0 + pi;
    int base = (p >> 12) << 12;
    float t = T[(size_t)p*64 + lane];
    const int* ir = idx + (size_t)p*KK;
    float mx = -INFINITY, mn = INFINITY;
    for (int k = 0; k < KK; ++k){
      int j = ir[k];
      float v = U[(size_t)(base + j)*64 + lane] + t;
      s += v; ss += v*v;
      mx = fmaxf(mx, v); mn = fminf(mn, v);
    }
    vmax[(size_t)p*64 + lane] = mx;
    vmin[(size_t)p*64 + lane] = mn;
  }
  __shared__ float rs[4][64], rss[4][64];
  rs[g][lane] = s; rss[g][lane] = ss;
  __syncthreads();
  if (g == 0){
    s  = rs[0][lane]+rs[1][lane]+rs[2][lane]+rs[3][lane];
    ss = rss[0][lane]+rss[1][lane]+rss[2][lane]+rss[3][lane];
    psum[(size_t)blockIdx.x*64 + lane] = s;
    psumsq[(size_t)blockIdx.x*64 + lane] = ss;
  }
}

// ---- elementwise: x_out[p,o] = lrelu(s*(s>=0?vmax:vmin)+t) -> xcat[:, ofs:ofs+64]
__global__ void gapply_kernel(const float* __restrict__ vmax, const float* __restrict__ vmin,
                              const float* __restrict__ scale, const float* __restrict__ shift,
                              float* __restrict__ xcat, int ofs){
  int i = blockIdx.x*256 + threadIdx.x;
  int p = i >> 6, o = i & 63;
  float s = scale[o];
  float v = (s >= 0.f) ? vmax[i] : vmin[i];
  xcat[(size_t)p*192 + ofs + o] = lrelu(s*v + shift[o]);
}

// ---- point-major matmul, 128p x 64o tile, 8x4 acc/thread (conv6), split staging.
__global__ void __launch_bounds__(256, 2)
mm_kernel(const float* __restrict__ in, int inStride, int inOfs,
          const float* __restrict__ W, int wStride,
          float* __restrict__ out, int outStride,
          const float* __restrict__ bias, int O, int I,
          const float* __restrict__ bnScale, const float* __restrict__ bnShift){
  __shared__ float As[64*AS_STRIDE + 64];
  __shared__ float Ws[64*WS_STRIDE + 64];
  int tid = threadIdx.x;
  int p0 = blockIdx.x*128, o0 = blockIdx.y*64;
  int psub = (tid >> 4)*8, osub = (tid & 15)*4;
  int cgrp = (tid & 15)*4;
  float acc[8][4] = {};
  for (int cc = 0; cc < I; cc += 64){
    float4 sc4 = make_float4(1.f,1.f,1.f,1.f), sh4 = make_float4(0.f,0.f,0.f,0.f);
    if (bnScale){
      sc4 = *(const float4*)(bnScale + cc + cgrp);
      sh4 = *(const float4*)(bnShift + cc + cgrp);
    }
    float4 vin[8], vw[4];
    #pragma unroll
    for (int j = 0; j < 8; ++j){
      int row = (tid + 256*j) >> 4;
      vin[j] = *(const float4*)(in + (size_t)(p0+row)*inStride + inOfs + cc + cgrp);
    }
    #pragma unroll
    for (int j = 0; j < 4; ++j){
      int row = (tid + 256*j) >> 4;
      vw[j] = *(const float4*)(W + (size_t)(o0+row)*wStride + cc + cgrp);
    }
    #pragma unroll
    for (int j = 0; j < 8; ++j){
      int row = (tid + 256*j) >> 4, c4 = cgrp;
      float4 v = vin[j];
      if (bnScale){
        v.x = lrelu(v.x*sc4.x + sh4.x); v.y = lrelu(v.y*sc4.y + sh4.y);
        v.z = lrelu(v.z*sc4.z + sh4.z); v.w = lrelu(v.w*sc4.w + sh4.w);
      }
      As[(c4+0)*AS_STRIDE+SKEW(c4+0)+row]=v.x; As[(c4+1)*AS_STRIDE+SKEW(c4+1)+row]=v.y;
      As[(c4+2)*AS_STRIDE+SKEW(c4+2)+row]=v.z; As[(c4+3)*AS_STRIDE+SKEW(c4+3)+row]=v.w;
    }
    #pragma unroll
    for (int j = 0; j < 4; ++j){
      int row = (tid + 256*j) >> 4, c4 = cgrp;
      float4 v = vw[j];
      Ws[(c4+0)*WS_STRIDE+SKEW(c4+0)+row]=v.x; Ws[(c4+1)*WS_STRIDE+SKEW(c4+1)+row]=v.y;
      Ws[(c4+2)*WS_STRIDE+SKEW(c4+2)+row]=v.z; Ws[(c4+3)*WS_STRIDE+SKEW(c4+3)+row]=v.w;
    }
    __syncthreads();
    for (int c = 0; c < 64; ++c){
      const float* arow = &As[c*AS_STRIDE + SKEW(c)];
      const float* brow = &Ws[c*WS_STRIDE + SKEW(c)];
      float4 a0 = *(const float4*)&arow[psub];
      float4 a1 = *(const float4*)&arow[psub + 4];
      float4 bb = *(const float4*)&brow[osub];
      float av[8] = {a0.x,a0.y,a0.z,a0.w,a1.x,a1.y,a1.z,a1.w};
      float bv[4] = {bb.x,bb.y,bb.z,bb.w};
      #pragma unroll
      for (int i = 0; i < 8; ++i)
        #pragma unroll
        for (int j = 0; j < 4; ++j)
          acc[i][j] += av[i]*bv[j];
    }
    __syncthreads();
  }
  int bIdx = p0 >> 12;
  float bb0=0.f, bb1=0.f, bb2=0.f, bb3=0.f;
  if (bias){
    bb0 = bias[bIdx*O + o0 + osub + 0];
    bb1 = bias[bIdx*O + o0 + osub + 1];
    bb2 = bias[bIdx*O + o0 + osub + 2];
    bb3 = bias[bIdx*O + o0 + osub + 3];
  }
  #pragma unroll
  for (int i = 0; i < 8; ++i){
    float4 w;
    w.x = acc[i][0]+bb0; w.y = acc[i][1]+bb1; w.z = acc[i][2]+bb2; w.w = acc[i][3]+bb3;
    *(float4*)(out + (size_t)(p0+psub+i)*outStride + o0 + osub) = w;
  }
}

// ---- point-major matmul, 64p x 64o tile, 4x4 acc/thread (conv7).
// Same 64-c staging chunks and ascending-c per-element FMA chain as mm_kernel
// -> bit-identical outputs. Grid (NPT/64, O/64) = 512 blocks = 2 blocks/CU
// (conv7 via mm_kernel was 256 blocks = 1/CU, occupancy-starved).
__global__ void __launch_bounds__(256, 2)
mm64_kernel(const float* __restrict__ in, int inStride, int inOfs,
            const float* __restrict__ W, int wStride,
            float* __restrict__ out, int outStride,
            int O, int I,
            const float* __restrict__ bnScale, const float* __restrict__ bnShift){
  __shared__ float As[64*WS_STRIDE + 64];
  __shared__ float Ws[64*WS_STRIDE + 64];
  int tid = threadIdx.x;
  int p0 = blockIdx.x*64, o0 = blockIdx.y*64;
  int psub = (tid >> 4)*4, osub = (tid & 15)*4;
  int cgrp = (tid & 15)*4;
  float acc[4][4] = {};
  for (int cc = 0; cc < I; cc += 64){
    float4 sc4 = make_float4(1.f,1.f,1.f,1.f), sh4 = make_float4(0.f,0.f,0.f,0.f);
    if (bnScale){
      sc4 = *(const float4*)(bnScale + cc + cgrp);
      sh4 = *(const float4*)(bnShift + cc + cgrp);
    }
    float4 vin[4], vw[4];
    #pragma unroll
    for (int j = 0; j < 4; ++j){
      int row = (tid + 256*j) >> 4;     // 0..63
      vin[j] = *(const float4*)(in + (size_t)(p0+row)*inStride + inOfs + cc + cgrp);
      vw[j]  = *(const float4*)(W + (size_t)(o0+row)*wStride + cc + cgrp);
    }
    __syncthreads();                    // WAR: prev iter reads done
    #pragma unroll
    for (int j = 0; j < 4; ++j){
      int row = (tid + 256*j) >> 4, c4 = cgrp;
      float4 v = vin[j];
      if (bnScale){
        v.x = lrelu(v.x*sc4.x + sh4.x); v.y = lrelu(v.y*sc4.y + sh4.y);
        v.z = lrelu(v.z*sc4.z + sh4.z); v.w = lrelu(v.w*sc4.w + sh4.w);
      }
      As[(c4+0)*WS_STRIDE+SKEW(c4+0)+row]=v.x; As[(c4+1)*WS_STRIDE+SKEW(c4+1)+row]=v.y;
      As[(c4+2)*WS_STRIDE+SKEW(c4+2)+row]=v.z; As[(c4+3)*WS_STRIDE+SKEW(c4+3)+row]=v.w;
      float4 w = vw[j];
      Ws[(c4+0)*WS_STRIDE+SKEW(c4+0)+row]=w.x; Ws[(c4+1)*WS_STRIDE+SKEW(c4+1)+row]=w.y;
      Ws[(c4+2)*WS_STRIDE+SKEW(c4+2)+row]=w.z; Ws[(c4+3)*WS_STRIDE+SKEW(c4+3)+row]=w.w;
    }
    __syncthreads();
    for (int c = 0; c < 64; ++c){
      const float* arow = &As[c*WS_STRIDE + SKEW(c)];
      const float* brow = &Ws[c*WS_STRIDE + SKEW(c)];
      float4 a0 = *(const float4*)&arow[psub];
      float4 bb = *(const float4*)&brow[osub];
      float av[4] = {a0.x,a0.y,a0.z,a0.w};
      float bv[4] = {bb.x,bb.y,bb.z,bb.w};
      #pragma unroll
      for (int i = 0; i < 4; ++i)
        #pragma unroll
        for (int j = 0; j < 4; ++j)
          acc[i][j] += av[i]*bv[j];
    }
  }
  #pragma unroll
  for (int i = 0; i < 4; ++i){
    float4 w;
    w.x = acc[i][0]; w.y = acc[i][1]; w.z = acc[i][2]; w.w = acc[i][3];
    *(float4*)(out + (size_t)(p0+psub+i)*outStride + o0 + osub) = w;
  }
}

// ---- point-major matmul, 128p x 128o tile, 8x8 acc/thread, split fragments,
// split staging (conv5).
__global__ void __launch_bounds__(256, 2)
mm128_kernel(const float* __restrict__ in, int inStride, int inOfs,
             const float* __restrict__ W, int wStride,
             float* __restrict__ out, int outStride,
             const float* __restrict__ bias, int O, int I,
             const float* __restrict__ bnScale, const float* __restrict__ bnShift){
  __shared__ float As[64*AS_STRIDE + 64];
  __shared__ float Ws[64*AS_STRIDE + 64];
  int tid = threadIdx.x;
  int p0 = blockIdx.x*128, o0 = blockIdx.y*128;
  int pA = (tid >> 4)*4, oB = (tid & 15)*4;
  int cgrp = (tid & 15)*4;
  float acc[8][8] = {};
  for (int cc = 0; cc < I; cc += 64){
    float4 sc4 = make_float4(1.f,1.f,1.f,1.f), sh4 = make_float4(0.f,0.f,0.f,0.f);
    if (bnScale){
      sc4 = *(const float4*)(bnScale + cc + cgrp);
      sh4 = *(const float4*)(bnShift + cc + cgrp);
    }
    float4 vin[8], vw[8];
    #pragma unroll
    for (int j = 0; j < 8; ++j){
      int row = (tid + 256*j) >> 4;
      vin[j] = *(const float4*)(in + (size_t)(p0+row)*inStride + inOfs + cc + cgrp);
      vw[j]  = *(const float4*)(W + (size_t)(o0+row)*wStride + cc + cgrp);
    }
    #pragma unroll
    for (int j = 0; j < 8; ++j){
      int row = (tid + 256*j) >> 4, c4 = cgrp;
      float4 v = vin[j];
      if (bnScale){
        v.x = lrelu(v.x*sc4.x + sh4.x); v.y = lrelu(v.y*sc4.y + sh4.y);
        v.z = lrelu(v.z*sc4.z + sh4.z); v.w = lrelu(v.w*sc4.w + sh4.w);
      }
      As[(c4+0)*AS_STRIDE+SKEW(c4+0)+row]=v.x; As[(c4+1)*AS_STRIDE+SKEW(c4+1)+row]=v.y;
      As[(c4+2)*AS_STRIDE+SKEW(c4+2)+row]=v.z; As[(c4+3)*AS_STRIDE+SKEW(c4+3)+row]=v.w;
      float4 w = vw[j];
      Ws[(c4+0)*AS_STRIDE+SKEW(c4+0)+row]=w.x; Ws[(c4+1)*AS_STRIDE+SKEW(c4+1)+row]=w.y;
      Ws[(c4+2)*AS_STRIDE+SKEW(c4+2)+row]=w.z; Ws[(c4+3)*AS_STRIDE+SKEW(c4+3)+row]=w.w;
    }
    __syncthreads();
    for (int c = 0; c < 64; ++c){
      const float* arow = &As[c*AS_STRIDE + SKEW(c)];
      const float* brow = &Ws[c*AS_STRIDE + SKEW(c)];
      float4 a0 = *(const float4*)&arow[pA];
      float4 a1 = *(const float4*)&arow[pA + 64];
      float4 b0 = *(const float4*)&brow[oB];
      float4 b1 = *(const float4*)&brow[oB + 64];
      float av[8] = {a0.x,a0.y,a0.z,a0.w,a1.x,a1.y,a1.z,a1.w};
      float bv[8] = {b0.x,b0.y,b0.z,b0.w,b1.x,b1.y,b1.z,b1.w};
      #pragma unroll
      for (int i = 0; i < 8; ++i)
        #pragma unroll
        for (int j = 0; j < 8; ++j)
          acc[i][j] += av[i]*bv[j];
    }
    __syncthreads();
  }
  int bIdx = p0 >> 12;
  float bb[8] = {0.f,0.f,0.f,0.f,0.f,0.f,0.f,0.f};
  if (bias){
    #pragma unroll
    for (int j = 0; j < 4; ++j){
      bb[j]   = bias[bIdx*O + o0 + oB + j];
      bb[4+j] = bias[bIdx*O + o0 + 64 + oB + j];
    }
  }
  #pragma unroll
  for (int h = 0; h < 2; ++h){
    #pragma unroll
    for (int i = 0; i < 4; ++i){
      int row = p0 + h*64 + pA + i;
      int ai = h*4 + i;
      float4 w0, w1;
      w0.x = acc[ai][0]+bb[0]; w0.y = acc[ai][1]+bb[1];
      w0.z = acc[ai][2]+bb[2]; w0.w = acc[ai][3]+bb[3];
      w1.x = acc[ai][4]+bb[4]; w1.y = acc[ai][5]+bb[5];
      w1.z = acc[ai][6]+bb[6]; w1.w = acc[ai][7]+bb[7];
      float* orow = out + (size_t)row*outStride + o0;
      *(float4*)(orow + oB) = w0;
      *(float4*)(orow + 64 + oB) = w1;
    }
  }
}

// ---- conv4 FUSED with stats: computes the 128x128 r4 tile in registers, then
// reduces in-block to per-channel sum/sumsq partials + per-(tile,ch) max/min.
// r4 is NEVER materialized (saves its 33.5 MB write + 33.5 MB stats re-read).
__global__ void __launch_bounds__(256, 2)
conv4stats_kernel(const float* __restrict__ xcat, const float* __restrict__ W4,
                  float* __restrict__ psum, float* __restrict__ psumsq,
                  float* __restrict__ pmax, float* __restrict__ pmin){
  __shared__ float As[64*AS_STRIDE + 64];
  __shared__ float Ws[64*AS_STRIDE + 64];
  int tid = threadIdx.x;
  int p0 = blockIdx.x*128, o0 = blockIdx.y*128;
  int pA = (tid >> 4)*4, oB = (tid & 15)*4;
  int cgrp = (tid & 15)*4;
  float4 vin[8], vw[8];
  #pragma unroll
  for (int j = 0; j < 8; ++j){
    int row = (tid + 256*j) >> 4;
    vin[j] = *(const float4*)(xcat + (size_t)(p0+row)*192 + 128 + cgrp);
    vw[j]  = *(const float4*)(W4 + (size_t)(o0+row)*64 + cgrp);
  }
  #pragma unroll
  for (int j = 0; j < 8; ++j){
    int row = (tid + 256*j) >> 4, c4 = cgrp;
    float4 v = vin[j];
    As[(c4+0)*AS_STRIDE+SKEW(c4+0)+row]=v.x; As[(c4+1)*AS_STRIDE+SKEW(c4+1)+row]=v.y;
    As[(c4+2)*AS_STRIDE+SKEW(c4+2)+row]=v.z; As[(c4+3)*AS_STRIDE+SKEW(c4+3)+row]=v.w;
    float4 w = vw[j];
    Ws[(c4+0)*AS_STRIDE+SKEW(c4+0)+row]=w.x; Ws[(c4+1)*AS_STRIDE+SKEW(c4+1)+row]=w.y;
    Ws[(c4+2)*AS_STRIDE+SKEW(c4+2)+row]=w.z; Ws[(c4+3)*AS_STRIDE+SKEW(c4+3)+row]=w.w;
  }
  __syncthreads();
  float acc[8][8] = {};
  for (int c = 0; c < 64; ++c){
    const float* arow = &As[c*AS_STRIDE + SKEW(c)];
    const float* brow = &Ws[c*AS_STRIDE + SKEW(c)];
    float4 a0 = *(const float4*)&arow[pA];
    float4 a1 = *(const float4*)&arow[pA + 64];
    float4 b0 = *(const float4*)&brow[oB];
    float4 b1 = *(const float4*)&brow[oB + 64];
    float av[8] = {a0.x,a0.y,a0.z,a0.w,a1.x,a1.y,a1.z,a1.w};
    float bv[8] = {b0.x,b0.y,b0.z,b0.w,b1.x,b1.y,b1.z,b1.w};
    #pragma unroll
    for (int i = 0; i < 8; ++i)
      #pragma unroll
      for (int j = 0; j < 8; ++j)
        acc[i][j] += av[i]*bv[j];
  }
  // per-thread column partials over its 8 rows (fixed order i=0..7)
  float cs[8], cq[8], cmx[8], cmn[8];
  #pragma unroll
  for (int j = 0; j < 8; ++j){
    float s = 0.f, q = 0.f, mx = -INFINITY, mn = INFINITY;
    #pragma unroll
    for (int i = 0; i < 8; ++i){
      float v = acc[i][j];
      s += v; q += v*v; mx = fmaxf(mx, v); mn = fminf(mn, v);
    }
    cs[j]=s; cq[j]=q; cmx[j]=mx; cmn[j]=mn;
  }
  __syncthreads();   // done reading As/Ws; reuse as scratch
  int r = tid >> 4;
  #pragma unroll
  for (int j = 0; j < 8; ++j){
    int col = (j < 4) ? (oB + j) : (64 + oB + (j-4));
    As[r*128 + col]        = cs[j];
    As[2048 + r*128 + col] = cq[j];
    Ws[r*128 + col]        = cmx[j];
    Ws[2048 + r*128 + col] = cmn[j];
  }
  __syncthreads();
  if (tid < 128){
    float ts = 0.f, tq = 0.f, tm = -INFINITY, tn = INFINITY;
    for (int rr = 0; rr < 16; ++rr){
      ts += As[rr*128 + tid];
      tq += As[2048 + rr*128 + tid];
      tm = fmaxf(tm, Ws[rr*128 + tid]);
      tn = fminf(tn, Ws[2048 + rr*128 + tid]);
    }
    size_t slot = (size_t)blockIdx.x*512 + o0 + tid;
    psum[slot] = ts; psumsq[slot] = tq; pmax[slot] = tm; pmin[slot] = tn;
  }
}

// lrelu(s*v+t) monotone in v: use max if s>=0 else min  (32 tiles per batch)
__global__ void x6v_kernel(const float* __restrict__ pmax, const float* __restrict__ pmin,
                           const float* __restrict__ scale, const float* __restrict__ shift,
                           float* __restrict__ x6v){
  int t = blockIdx.x*256 + threadIdx.x;
  int b = t >> 9, o = t & 511;
  float mx = -INFINITY, mn = INFINITY;
  for (int pt = b*32; pt < b*32+32; ++pt){
    mx = fmaxf(mx, pmax[(size_t)pt*512 + o]);
    mn = fminf(mn, pmin[(size_t)pt*512 + o]);
  }
  float s = scale[o];
  float v = (s >= 0.f) ? mx : mn;
  x6v[t] = lrelu(s*v + shift[o]);
}

// bias5[b,o] = sum_c W5[o, 192+c] * x6v[b,c]   (the broadcast part of the concat)
__global__ void bias5_kernel(const float* __restrict__ W5, const float* __restrict__ x6v,
                             float* __restrict__ b5){
  __shared__ float xl[512];
  int tid = threadIdx.x;
  int t = blockIdx.x*256 + tid;
  int b = t >> 9, o = t & 511;
  for (int i = tid; i < 512; i += 256) xl[i] = x6v[(b<<9) + i];
  __syncthreads();
  const float* wr = W5 + (size_t)o*704 + 192;
  float acc = 0.f;
  for (int c = 0; c < 512; ++c) acc += wr[c]*xl[c];
  b5[t] = acc;
}

// ---- conv8 (128->2) + bias over raw r7 with BN7+lrelu applied inline
__global__ void conv8_kernel(const float* __restrict__ r7, const float* __restrict__ W8,
                             const float* __restrict__ bias8,
                             const float* __restrict__ scale, const float* __restrict__ shift,
                             float* __restrict__ out){
  __shared__ float Wl[256];
  __shared__ float scl[128], shl[128];
  int tid = threadIdx.x;
  Wl[tid] = W8[tid];
  if (tid < 128){ scl[tid] = scale[tid]; shl[tid] = shift[tid]; }
  __syncthreads();
  int p = blockIdx.x*256 + tid;
  int b = p >> 12, n = p & 4095;
  const float4* row = (const float4*)(r7 + (size_t)p*128);
  float a0 = 0.f, a1 = 0.f;
  #pragma unroll
  for (int i = 0; i < 32; ++i){
    float4 v = row[i];
    v.x = lrelu(v.x*scl[i*4+0] + shl[i*4+0]);
    v.y = lrelu(v.y*scl[i*4+1] + shl[i*4+1]);
    v.z = lrelu(v.z*scl[i*4+2] + shl[i*4+2]);
    v.w = lrelu(v.w*scl[i*4+3] + shl[i*4+3]);
    a0 += v.x*Wl[i*4] + v.y*Wl[i*4+1] + v.z*Wl[i*4+2] + v.w*Wl[i*4+3];
    a1 += v.x*Wl[128+i*4] + v.y*Wl[128+i*4+1] + v.z*Wl[128+i*4+2] + v.w*Wl[128+i*4+3];
  }
  out[(size_t)(b*2+0)*NN + n] = a0 + bias8[0];
  out[(size_t)(b*2+1)*NN + n] = a1 + bias8[1];
}

extern "C" void kernel_launch(void* const* d_in, const int* in_sizes, int n_in,
                              void* d_out, int out_size, void* d_ws, size_t ws_size,
                              hipStream_t stream){
  const float* x     = (const float*)d_in[0];
  const float* W1    = (const float*)d_in[1];
  const float* W2    = (const float*)d_in[2];
  const float* W3    = (const float*)d_in[3];
  const float* W4    = (const float*)d_in[4];
  const float* W5    = (const float*)d_in[5];
  const float* W6    = (const float*)d_in[6];
  const float* W7    = (const float*)d_in[7];
  const float* W8    = (const float*)d_in[8];
  const float* bias8 = (const float*)d_in[9];
  const float* gamma[8]; const float* beta[8];
  for (int i = 1; i <= 7; ++i){
    gamma[i] = (const float*)d_in[10 + 2*(i-1)];
    beta[i]  = (const float*)d_in[11 + 2*(i-1)];
  }
  float* out = (float*)d_out;

  float* ws = (float*)d_ws;
  size_t off = 0;
  float* xcat  = ws + off; off += (size_t)NPT*192;   // x1|x2|x3 packed, stride 192
  float* U     = ws + off; off += (size_t)NPT*64;
  float* T     = ws + off; off += (size_t)NPT*64;
  float* xx    = ws + off; off += NPT;
  int*   idx   = (int*)(ws + off); off += (size_t)NPT*KK;
  float* psum  = ws + off; off += 128*512;
  float* psumsq= ws + off; off += 128*512;
  float* pmax  = ws + off; off += 128*512;
  float* pmin  = ws + off; off += 128*512;
  float* scale = ws + off; off += 512;
  float* shift = ws + off; off += 512;
  float* x6v   = ws + off; off += 2048;
  float* b5    = ws + off; off += 2048;
  float* big   = ws + off;   // time-shared: dist (knn) / vmax|vmin (gather) / r5|r6|r7
  float* dist  = big;                               // 16.8M floats (one batch)
  float* vmaxB = big;                               // NPT*64, live only between knn rounds
  float* vminB = big + (size_t)NPT*64;
  float* r5    = big;
  float* r6    = big + (size_t)NPT*512;
  float* r7    = big + (size_t)NPT*512 + (size_t)NPT*256;
  // gmax overlays U|T (dead during knn): 4096 rows x 512 groups u32 = 2M words
  unsigned* gmaxU = (unsigned*)U;

  // ---- stage 1: conv1 + BN(train stats) + lrelu -> x1 (xcat[:,0:64])
  conv1_kernel<<<NPT/4, 256, 0, stream>>>(x, W1, xcat);
  stats_pm_kernel<<<dim3(1,64), 256, 0, stream>>>(xcat, 192, 0, psum, psumsq, 64);
  bn_finalize_kernel<<<1, 64, 0, stream>>>(psum, psumsq, 64, gamma[1], beta[1], scale, shift, 1.f/16384.f, 64);
  apply_bn_kernel<<<NPT*64/256, 256, 0, stream>>>(xcat, 192, 0, 6, scale, shift);

  // ---- knn on x1 (triangular dist+gmax; filtered exact top-20)
  xx_kernel<<<NPT/256, 256, 0, stream>>>(xcat, 192, 0, xx);
  for (int b = 0; b < BB; ++b){
    dist_kernel<<<dim3(32,32), 256, 0, stream>>>(xcat, 0, xx, dist, gmaxU, b);
    topk_kernel<<<NN/4, 256, 0, stream>>>(dist, gmaxU, idx + (size_t)b*NN*KK);
  }

  // ---- stage 2: edge-conv (W2): single gather pass (stats + vmax/vmin), then elementwise
  ut_kernel<<<NPT/4, 256, 0, stream>>>(xcat, 0, W2, U, T);
  gather_kernel<<<256, 256, 0, stream>>>(U, T, idx, psum, psumsq, vmaxB, vminB);
  bn_finalize_kernel<<<1, 64, 0, stream>>>(psum, psumsq, 256, gamma[2], beta[2], scale, shift, 1.f/327680.f, 64);
  gapply_kernel<<<NPT*64/256, 256, 0, stream>>>(vmaxB, vminB, scale, shift, xcat, 64);

  // ---- knn on x2
  xx_kernel<<<NPT/256, 256, 0, stream>>>(xcat, 192, 64, xx);
  for (int b = 0; b < BB; ++b){
    dist_kernel<<<dim3(32,32), 256, 0, stream>>>(xcat, 64, xx, dist, gmaxU, b);
    topk_kernel<<<NN/4, 256, 0, stream>>>(dist, gmaxU, idx + (size_t)b*NN*KK);
  }

  // ---- stage 3: edge-conv (W3) -> x3
  ut_kernel<<<NPT/4, 256, 0, stream>>>(xcat, 64, W3, U, T);
  gather_kernel<<<256, 256, 0, stream>>>(U, T, idx, psum, psumsq, vmaxB, vminB);
  bn_finalize_kernel<<<1, 64, 0, stream>>>(psum, psumsq, 256, gamma[3], beta[3], scale, shift, 1.f/327680.f, 64);
  gapply_kernel<<<NPT*64/256, 256, 0, stream>>>(vmaxB, vminB, scale, shift, xcat, 128);

  // ---- stage 4: conv4 fused with stats (r4 never materialized)
  conv4stats_kernel<<<dim3(NPT/128, 4), 256, 0, stream>>>(xcat, W4, psum, psumsq, pmax, pmin);
  bn_finalize_kernel<<<1, 512, 0, stream>>>(psum, psumsq, 128, gamma[4], beta[4], scale, shift, 1.f/16384.f, 512);
  x6v_kernel<<<8, 256, 0, stream>>>(pmax, pmin, scale, shift, x6v);
  bias5_kernel<<<8, 256, 0, stream>>>(W5, x6v, b5);

  // ---- stage 5: conv5 (704->512) = mm128 over packed 192 + bias5; r5 stays RAW
  mm128_kernel<<<dim3(NPT/128, 4), 256, 0, stream>>>(xcat, 192, 0, W5, 704, r5, 512, b5, 512, 192, nullptr, nullptr);
  stats_pm_kernel<<<dim3(8,64), 256, 0, stream>>>(r5, 512, 0, psum, psumsq, 512);
  bn_finalize_kernel<<<1, 512, 0, stream>>>(psum, psumsq, 64, gamma[5], beta[5], scale, shift, 1.f/16384.f, 512);

  // ---- stage 6: conv6 (512->256), BN5+lrelu on load; r6 stays RAW.
  // 64-out tiles (mm_kernel) -> 512 blocks = 2 blocks/CU.
  mm_kernel<<<dim3(NPT/128, 4), 256, 0, stream>>>(r5, 512, 0, W6, 512, r6, 256, nullptr, 256, 512, scale, shift);
  stats_pm_kernel<<<dim3(4,64), 256, 0, stream>>>(r6, 256, 0, psum, psumsq, 256);
  bn_finalize_kernel<<<1, 256, 0, stream>>>(psum, psumsq, 64, gamma[6], beta[6], scale, shift, 1.f/16384.f, 256);

  // ---- stage 7: conv7 (256->128), BN6+lrelu on load; r7 stays RAW.
  // 64p x 64o tiles -> 512 blocks = 2 blocks/CU (was 256 = 1/CU via mm_kernel).
  mm64_kernel<<<dim3(NPT/64, 2), 256, 0, stream>>>(r6, 256, 0, W7, 256, r7, 128, 128, 256, scale, shift);
  stats_pm_kernel<<<dim3(2,64), 256, 0, stream>>>(r7, 128, 0, psum, psumsq, 128);
  bn_finalize_kernel<<<1, 128, 0, stream>>>(psum, psumsq, 64, gamma[7], beta[7], scale, shift, 1.f/16384.f, 128);

  // ---- stage 8: conv8 (128->2) + bias, BN7+lrelu applied inline
  conv8_kernel<<<NPT/256, 256, 0, stream>>>(r7, W8, bias8, scale, shift, out);
}

// Round 10
// 1089.017 us; speedup vs baseline: 1.7147x; 1.0065x over previous
//
#include <hip/hip_runtime.h>
#include <math.h>

#define NN 4096
#define BB 4
#define NPT (NN*BB)
#define KK 20
#define EPSB 1e-5f

#define AS_STRIDE 132   // 128-point c-row, padded
#define WS_STRIDE 68    // 64-col c-row, padded
// Non-wrapping per-channel skew: staging writes 2-way (free), reads clean,
// all offsets multiples of 4 floats so float4 reads stay 16B-aligned.
#define SKEW(c) ((((((c)>>2)&7))<<2) + (((c)>>5)*28))

__device__ __forceinline__ float lrelu(float x){ return x >= 0.f ? x : 0.2f*x; }

// monotone float->uint key: order(key) == order(float)
__device__ __forceinline__ unsigned fkey(float x){
  unsigned u = __float_as_uint(x);
  return u ^ (unsigned)(((int)u >> 31) | 0x80000000);
}

// ---- stage 1: conv1 (3->64), writes raw into xcat[:, 0:64] (point-major, row stride 192)
__global__ void conv1_kernel(const float* __restrict__ x, const float* __restrict__ W1,
                             float* __restrict__ xcat){
  __shared__ float Wl[192];
  int tid = threadIdx.x;
  if (tid < 192) Wl[tid] = W1[tid];
  __syncthreads();
  int p = blockIdx.x*4 + (tid >> 6);
  int o = tid & 63;
  int b = p >> 12, n = p & 4095;
  const float* xb = x + (size_t)b*3*NN + n;
  float acc = Wl[o*3+0]*xb[0] + Wl[o*3+1]*xb[NN] + Wl[o*3+2]*xb[2*NN];
  xcat[(size_t)p*192 + o] = acc;
}

// ---- per-channel partial stats for point-major (NPT, C) buffer; deterministic slots
__global__ void stats_pm_kernel(const float* __restrict__ buf, int stride, int ofs,
                                float* __restrict__ psum, float* __restrict__ psumsq, int C){
  int tid = threadIdx.x;
  int lane = tid & 63, g = tid >> 6;
  int o = blockIdx.x*64 + lane;
  int p0 = blockIdx.y*256 + g*64;
  float s = 0.f, ss = 0.f;
  for (int i = 0; i < 64; ++i){
    float v = buf[(size_t)(p0+i)*stride + ofs + o];
    s += v; ss += v*v;
  }
  __shared__ float rs[4][64], rss[4][64];
  rs[g][lane] = s; rss[g][lane] = ss;
  __syncthreads();
  if (g == 0){
    s  = rs[0][lane]+rs[1][lane]+rs[2][lane]+rs[3][lane];
    ss = rss[0][lane]+rss[1][lane]+rss[2][lane]+rss[3][lane];
    psum[(size_t)blockIdx.y*C + o] = s;
    psumsq[(size_t)blockIdx.y*C + o] = ss;
  }
}

// deterministic finalize: serial sum over nparts partials per channel
__global__ void bn_finalize_kernel(const float* __restrict__ psum, const float* __restrict__ psumsq,
                                   int nparts,
                                   const float* __restrict__ gamma, const float* __restrict__ beta,
                                   float* __restrict__ scale, float* __restrict__ shift,
                                   float invcnt, int C){
  int o = threadIdx.x + blockIdx.x*blockDim.x;
  if (o >= C) return;
  float s = 0.f, ss = 0.f;
  for (int i = 0; i < nparts; ++i){
    s  += psum[(size_t)i*C + o];
    ss += psumsq[(size_t)i*C + o];
  }
  float m = s*invcnt;
  float v = ss*invcnt - m*m;
  v = fmaxf(v, 0.f);
  float sc = gamma[o] * rsqrtf(v + EPSB);
  scale[o] = sc;
  shift[o] = beta[o] - m*sc;
}

__global__ void apply_bn_kernel(float* __restrict__ buf, int stride, int ofs, int log2C,
                                const float* __restrict__ scale, const float* __restrict__ shift){
  int i = blockIdx.x*256 + threadIdx.x;
  int o = i & ((1<<log2C)-1);
  int p = i >> log2C;
  size_t a = (size_t)p*stride + ofs + o;
  float e = buf[a]*scale[o] + shift[o];
  buf[a] = lrelu(e);
}

// ---- ||x||^2 per point (64 features)
__global__ void xx_kernel(const float* __restrict__ xcat, int stride, int ofs,
                          float* __restrict__ xx){
  int p = blockIdx.x*256 + threadIdx.x;
  const float4* r = (const float4*)(xcat + (size_t)p*stride + ofs);
  float s = 0.f;
  #pragma unroll
  for (int i = 0; i < 16; ++i){ float4 v = r[i]; s += v.x*v.x + v.y*v.y + v.z*v.z + v.w*v.w; }
  xx[p] = s;
}

// ---- dist: TRIANGULAR 128n x 128m tiles (by<=bx) + mirror write. Bit-identical
// values to the verified kernel. ALSO writes per-(row,group-of-8) key-maxima
// (gmax, u32 keys) for the filtered topk. Group gid: cols {cb..cb+3,
// cb+64..cb+67}, cb = (gid>>4)*128 + (gid&15)*4. Each (row,gid) written once.
__global__ void __launch_bounds__(256, 2)
dist_kernel(const float* __restrict__ xcat, int ofs,
            const float* __restrict__ xx, float* __restrict__ dist,
            unsigned* __restrict__ gmaxp, int b){
  int bx = blockIdx.x, by = blockIdx.y;
  if (by > bx) return;                 // lower triangle filled by mirror
  __shared__ float As[64*AS_STRIDE + 64];
  __shared__ float Bs[64*AS_STRIDE + 64];
  int tid = threadIdx.x;
  int n0 = by*128, m0 = bx*128;        // row tile <= col tile
  const float* base = xcat + (size_t)b*NN*192 + ofs;
  int cgrp = (tid & 15)*4;
  float4 vin[8], vw[8];
  #pragma unroll
  for (int j = 0; j < 8; ++j){
    int row = (tid + 256*j) >> 4;
    vin[j] = *(const float4*)(base + (size_t)(n0+row)*192 + cgrp);
    vw[j]  = *(const float4*)(base + (size_t)(m0+row)*192 + cgrp);
  }
  #pragma unroll
  for (int j = 0; j < 8; ++j){
    int row = (tid + 256*j) >> 4, c4 = cgrp;
    float4 v = vin[j];
    As[(c4+0)*AS_STRIDE+SKEW(c4+0)+row]=v.x; As[(c4+1)*AS_STRIDE+SKEW(c4+1)+row]=v.y;
    As[(c4+2)*AS_STRIDE+SKEW(c4+2)+row]=v.z; As[(c4+3)*AS_STRIDE+SKEW(c4+3)+row]=v.w;
    float4 w = vw[j];
    Bs[(c4+0)*AS_STRIDE+SKEW(c4+0)+row]=w.x; Bs[(c4+1)*AS_STRIDE+SKEW(c4+1)+row]=w.y;
    Bs[(c4+2)*AS_STRIDE+SKEW(c4+2)+row]=w.z; Bs[(c4+3)*AS_STRIDE+SKEW(c4+3)+row]=w.w;
  }
  __syncthreads();
  int pA = (tid >> 4)*4, oB = (tid & 15)*4;
  float acc[8][8] = {};   // i: 0-3 rows pA+i, 4-7 rows pA+64+(i-4); j likewise cols
  for (int c = 0; c < 64; ++c){
    const float* arow = &As[c*AS_STRIDE + SKEW(c)];
    const float* brow = &Bs[c*AS_STRIDE + SKEW(c)];
    float4 a0 = *(const float4*)&arow[pA];
    float4 a1 = *(const float4*)&arow[pA + 64];
    float4 b0 = *(const float4*)&brow[oB];
    float4 b1 = *(const float4*)&brow[oB + 64];
    float av[8] = {a0.x,a0.y,a0.z,a0.w,a1.x,a1.y,a1.z,a1.w};
    float bv[8] = {b0.x,b0.y,b0.z,b0.w,b1.x,b1.y,b1.z,b1.w};
    #pragma unroll
    for (int i = 0; i < 8; ++i)
      #pragma unroll
      for (int j = 0; j < 8; ++j)
        acc[i][j] += av[i]*bv[j];
  }
  float xmv[8], xnv[8];
  #pragma unroll
  for (int j = 0; j < 4; ++j){
    xmv[j]   = xx[b*NN + m0 + oB + j];
    xmv[4+j] = xx[b*NN + m0 + 64 + oB + j];
    xnv[j]   = xx[b*NN + n0 + pA + j];
    xnv[4+j] = xx[b*NN + n0 + 64 + pA + j];
  }
  #pragma unroll
  for (int h = 0; h < 2; ++h){
    #pragma unroll
    for (int i = 0; i < 4; ++i){
      int row = n0 + h*64 + pA + i;
      float xn = xnv[h*4 + i];
      int ai = h*4 + i;
      float4 w0, w1;
      w0.x = 2.f*acc[ai][0] - xn - xmv[0]; w0.y = 2.f*acc[ai][1] - xn - xmv[1];
      w0.z = 2.f*acc[ai][2] - xn - xmv[2]; w0.w = 2.f*acc[ai][3] - xn - xmv[3];
      w1.x = 2.f*acc[ai][4] - xn - xmv[4]; w1.y = 2.f*acc[ai][5] - xn - xmv[5];
      w1.z = 2.f*acc[ai][6] - xn - xmv[6]; w1.w = 2.f*acc[ai][7] - xn - xmv[7];
      float* drow = dist + (size_t)row*NN + m0;
      *(float4*)(drow + oB) = w0;
      *(float4*)(drow + 64 + oB) = w1;
      unsigned gm = fkey(w0.x), t;
      t = fkey(w0.y); if (t > gm) gm = t;
      t = fkey(w0.z); if (t > gm) gm = t;
      t = fkey(w0.w); if (t > gm) gm = t;
      t = fkey(w1.x); if (t > gm) gm = t;
      t = fkey(w1.y); if (t > gm) gm = t;
      t = fkey(w1.z); if (t > gm) gm = t;
      t = fkey(w1.w); if (t > gm) gm = t;
      gmaxp[(size_t)row*512 + (bx<<4) + (oB>>2)] = gm;
    }
  }
  if (bx != by){
    // mirror: element (m,n) = ((2a - xx[m]) - xx[n]); float4 along contiguous n
    #pragma unroll
    for (int jh = 0; jh < 2; ++jh){
      #pragma unroll
      for (int jj = 0; jj < 4; ++jj){
        int j = jh*4 + jj;
        float xm = xmv[j];
        float4 lo, hi;
        lo.x = 2.f*acc[0][j] - xm - xnv[0];
        lo.y = 2.f*acc[1][j] - xm - xnv[1];
        lo.z = 2.f*acc[2][j] - xm - xnv[2];
        lo.w = 2.f*acc[3][j] - xm - xnv[3];
        hi.x = 2.f*acc[4][j] - xm - xnv[4];
        hi.y = 2.f*acc[5][j] - xm - xnv[5];
        hi.z = 2.f*acc[6][j] - xm - xnv[6];
        hi.w = 2.f*acc[7][j] - xm - xnv[7];
        int mrow = m0 + jh*64 + oB + jj;
        float* drow = dist + (size_t)mrow*NN + n0;
        *(float4*)(drow + pA) = lo;
        *(float4*)(drow + 64 + pA) = hi;
        unsigned gm = fkey(lo.x), t;
        t = fkey(lo.y); if (t > gm) gm = t;
        t = fkey(lo.z); if (t > gm) gm = t;
        t = fkey(lo.w); if (t > gm) gm = t;
        t = fkey(hi.x); if (t > gm) gm = t;
        t = fkey(hi.y); if (t > gm) gm = t;
        t = fkey(hi.z); if (t > gm) gm = t;
        t = fkey(hi.w); if (t > gm) gm = t;
        gmaxp[(size_t)mrow*512 + (by<<4) + (pA>>2)] = gm;
      }
    }
  }
}

// ---- topk v3b: group-max prefilter + exact selection. One wave per row.
// T = conservative threshold from a SHORTENED binary radix over the 512 group
// maxima: scan bits 31..16 only, with early exit once the passing-group count
// (20-need)+|act| <= 44. Any prefix-truncated T satisfies T <= T_exact <= v20
// (>=20 groups have gmax >= T), so the value-filter key>=T keeps every top-20
// value incl. ties -> selection stays exact. Candidates gathered to per-wave
// LDS; C<=64: 64-lane bitonic sort (value desc, index asc); C>64: exact
// fallback rescans dist directly (independent of the LDS buffer).
__global__ void __launch_bounds__(256)
topk_kernel(const float* __restrict__ dist, const unsigned* __restrict__ gmax,
            int* __restrict__ idxout){
  __shared__ unsigned lv[4][256], li[4][256];
  __shared__ unsigned lcnt[4];
  int wv = threadIdx.x >> 6, lane = threadIdx.x & 63;
  int n = blockIdx.x*4 + wv;
  const unsigned* grow = gmax + (size_t)n*512;
  unsigned g[8];
  #pragma unroll
  for (int j = 0; j < 8; ++j) g[j] = grow[j*64 + lane];
  if (lane == 0) lcnt[wv] = 0u;          // same-wave LDS ops are in-order
  unsigned prefix = 0u, act = 0xFFu; int need = KK; int tot = 512;
  for (int b = 31; b >= 16; --b){
    unsigned m = 0u;
    #pragma unroll
    for (int j = 0; j < 8; ++j) m |= ((g[j] >> b) & 1u) << j;
    unsigned c = (unsigned)__popc(m & act);
    #pragma unroll
    for (int s = 1; s < 64; s <<= 1) c += __shfl_xor(c, s);
    if ((int)c >= need){ act &= m; prefix |= (1u << b); tot = (int)c; }
    else { need -= (int)c; act &= ~m; tot -= (int)c; }
    if (KK - need + tot <= 44) break;    // few enough passing groups: stop
  }
  unsigned T = prefix;                    // conservative (<= exact 20th gmax)
  const float* drow = dist + (size_t)n*NN;
  #pragma unroll
  for (int j = 0; j < 8; ++j){
    if (g[j] >= T){
      int gid = j*64 + lane;
      int cbase = ((gid >> 4) << 7) + ((gid & 15) << 2);
      float4 v0 = *(const float4*)(drow + cbase);
      float4 v1 = *(const float4*)(drow + cbase + 64);
      unsigned k0=fkey(v0.x),k1=fkey(v0.y),k2=fkey(v0.z),k3=fkey(v0.w);
      unsigned k4=fkey(v1.x),k5=fkey(v1.y),k6=fkey(v1.z),k7=fkey(v1.w);
      int q = (k0>=T)+(k1>=T)+(k2>=T)+(k3>=T)+(k4>=T)+(k5>=T)+(k6>=T)+(k7>=T);
      unsigned pos = atomicAdd(&lcnt[wv], (unsigned)q);
      #define PUTC(kx,cofs) if (kx >= T){ if (pos < 256u){ lv[wv][pos]=kx; li[wv][pos]=(unsigned)(cbase+(cofs)); } pos++; }
      PUTC(k0,0) PUTC(k1,1) PUTC(k2,2) PUTC(k3,3)
      PUTC(k4,64) PUTC(k5,65) PUTC(k6,66) PUTC(k7,67)
      #undef PUTC
    }
  }
  unsigned C = lcnt[wv];                  // all wave atomics precede this read
  int* orow = idxout + (size_t)n*KK;
  if (C <= 64u){
    unsigned kv = 0u, ki = 0xFFFFFFFFu;   // dummy key 0 = -inf, never a real dist
    if (lane < (int)C){ kv = lv[wv][lane]; ki = li[wv][lane]; }
    #pragma unroll
    for (int k = 2; k <= 64; k <<= 1){
      #pragma unroll
      for (int j2 = k >> 1; j2 > 0; j2 >>= 1){
        unsigned ov = __shfl_xor(kv, j2);
        unsigned oi = __shfl_xor(ki, j2);
        bool iLower = ((lane & j2) == 0);
        bool dirDesc = ((lane & k) == 0);
        bool mineGr = (kv > ov) || (kv == ov && ki < oi);
        bool keep = dirDesc ? (iLower ? mineGr : !mineGr)
                            : (iLower ? !mineGr : mineGr);
        kv = keep ? kv : ov;
        ki = keep ? ki : oi;
      }
    }
    if (lane < KK) orow[lane] = (int)ki;
  } else {
    // rare exact fallback: rescan qualifying groups, per-lane reg top-20 + merge
    unsigned rv[KK], ri[KK];
    #pragma unroll
    for (int q = 0; q < KK; ++q){ rv[q]=0u; ri[q]=0xFFFFFFFFu; }
    #pragma unroll
    for (int j = 0; j < 8; ++j){
      if (g[j] >= T){
        int gid = j*64 + lane;
        int cbase = ((gid >> 4) << 7) + ((gid & 15) << 2);
        float4 v0 = *(const float4*)(drow + cbase);
        float4 v1 = *(const float4*)(drow + cbase + 64);
        float f0[8] = {v0.x,v0.y,v0.z,v0.w,v1.x,v1.y,v1.z,v1.w};
        #pragma unroll
        for (int t = 0; t < 8; ++t){
          unsigned u = fkey(f0[t]);
          unsigned ix = (unsigned)(cbase + ((t < 4) ? t : (60 + t)));
          bool beat = (u > rv[KK-1]) || (u == rv[KK-1] && ix < ri[KK-1]);
          if (u >= T && beat){
            unsigned pv = u, pi = ix;
            #pragma unroll
            for (int p = 0; p < KK; ++p){
              bool keep2 = (rv[p] > pv) || (rv[p] == pv && ri[p] < pi);
              unsigned nv = keep2 ? rv[p] : pv;
              unsigned ni = keep2 ? ri[p] : pi;
              pv = keep2 ? pv : rv[p];
              pi = keep2 ? pi : ri[p];
              rv[p] = nv; ri[p] = ni;
            }
          }
        }
      }
    }
    for (int q = 0; q < KK; ++q){
      unsigned bv = rv[0], bi = ri[0];
      #pragma unroll
      for (int s = 1; s < 64; s <<= 1){
        unsigned ov = __shfl_xor(bv, s);
        unsigned oi = __shfl_xor(bi, s);
        bool take = (ov > bv) || (ov == bv && oi < bi);
        bv = take ? ov : bv;
        bi = take ? oi : bi;
      }
      if (rv[0] == bv && ri[0] == bi){
        #pragma unroll
        for (int p = 0; p < KK-1; ++p){ rv[p] = rv[p+1]; ri[p] = ri[p+1]; }
        rv[KK-1] = 0u; ri[KK-1] = 0xFFFFFFFFu;
      }
      if (lane == 0) orow[q] = (int)bi;
    }
  }
}

// ---- U = W[:, :64] * x ; T = (W[:,64:] - W[:, :64]) * x  (per point, point-major out)
__global__ void ut_kernel(const float* __restrict__ xcat, int ofs, const float* __restrict__ W,
                          float* __restrict__ U, float* __restrict__ T){
  __shared__ float Wl[64*129];
  int tid = threadIdx.x;
  for (int i = tid; i < 64*128; i += 256){
    int o = i >> 7, c = i & 127;
    Wl[o*129 + c] = W[i];
  }
  __syncthreads();
  int g = tid >> 6, lane = tid & 63;
  int p = blockIdx.x*4 + g;
  float xv = xcat[(size_t)p*192 + ofs + lane];
  const float* wr = Wl + lane*129;
  float u = 0.f, t = 0.f;
  for (int c = 0; c < 64; ++c){
    float xc = __shfl(xv, c);
    float wa = wr[c], wb = wr[64+c];
    u += wa*xc;
    t += (wb - wa)*xc;
  }
  U[(size_t)p*64 + lane] = u;
  T[(size_t)p*64 + lane] = t;
}

// ---- ONE gather pass: v = U[j]+T[n] over k -> per-channel partial sum/sumsq
// (deterministic slots) AND per-(point,ch) vmax/vmin (lrelu-monotone max trick).
__global__ void gather_kernel(const float* __restrict__ U, const float* __restrict__ T,
                              const int* __restrict__ idx,
                              float* __restrict__ psum, float* __restrict__ psumsq,
                              float* __restrict__ vmax, float* __restrict__ vmin){
  int tid = threadIdx.x;
  int g = tid >> 6, lane = tid & 63;
  int p0 = blockIdx.x*64 + g*16;
  float s = 0.f, ss = 0.f;
  for (int pi = 0; pi < 16; ++pi){
    int p = p0 + pi;
    int base = (p >> 12) << 12;
    float t = T[(size_t)p*64 + lane];
    const int* ir = idx + (size_t)p*KK;
    float mx = -INFINITY, mn = INFINITY;
    for (int k = 0; k < KK; ++k){
      int j = ir[k];
      float v = U[(size_t)(base + j)*64 + lane] + t;
      s += v; ss += v*v;
      mx = fmaxf(mx, v); mn = fminf(mn, v);
    }
    vmax[(size_t)p*64 + lane] = mx;
    vmin[(size_t)p*64 + lane] = mn;
  }
  __shared__ float rs[4][64], rss[4][64];
  rs[g][lane] = s; rss[g][lane] = ss;
  __syncthreads();
  if (g == 0){
    s  = rs[0][lane]+rs[1][lane]+rs[2][lane]+rs[3][lane];
    ss = rss[0][lane]+rss[1][lane]+rss[2][lane]+rss[3][lane];
    psum[(size_t)blockIdx.x*64 + lane] = s;
    psumsq[(size_t)blockIdx.x*64 + lane] = ss;
  }
}

// ---- elementwise: x_out[p,o] = lrelu(s*(s>=0?vmax:vmin)+t) -> xcat[:, ofs:ofs+64]
__global__ void gapply_kernel(const float* __restrict__ vmax, const float* __restrict__ vmin,
                              const float* __restrict__ scale, const float* __restrict__ shift,
                              float* __restrict__ xcat, int ofs){
  int i = blockIdx.x*256 + threadIdx.x;
  int p = i >> 6, o = i & 63;
  float s = scale[o];
  float v = (s >= 0.f) ? vmax[i] : vmin[i];
  xcat[(size_t)p*192 + ofs + o] = lrelu(s*v + shift[o]);
}

// ---- point-major matmul, 128p x 64o tile, 8x4 acc/thread (conv5).
// 32-c staging chunks: LDS 26 KB -> 4+ blocks/CU at unchanged VGPR (~72,
// launch_bounds(256,2) keeps the 256-VGPR cap -> no spill; round-1's failure
// was the (256,4) cap, not the chunking). Per-element FMA chain still one
// ascending-c += sequence -> bit-identical outputs.
__global__ void __launch_bounds__(256, 2)
mm_kernel(const float* __restrict__ in, int inStride, int inOfs,
          const float* __restrict__ W, int wStride,
          float* __restrict__ out, int outStride,
          const float* __restrict__ bias, int O, int I,
          const float* __restrict__ bnScale, const float* __restrict__ bnShift){
  __shared__ float As[32*AS_STRIDE + 64];
  __shared__ float Ws[32*WS_STRIDE + 64];
  int tid = threadIdx.x;
  int p0 = blockIdx.x*128, o0 = blockIdx.y*64;
  int psub = (tid >> 4)*8, osub = (tid & 15)*4;
  int cgrp = (tid & 7)*4;
  float acc[8][4] = {};
  for (int cc = 0; cc < I; cc += 32){
    float4 sc4 = make_float4(1.f,1.f,1.f,1.f), sh4 = make_float4(0.f,0.f,0.f,0.f);
    if (bnScale){
      sc4 = *(const float4*)(bnScale + cc + cgrp);
      sh4 = *(const float4*)(bnShift + cc + cgrp);
    }
    float4 vin[4], vw[2];
    #pragma unroll
    for (int j = 0; j < 4; ++j){
      int row = (tid + 256*j) >> 3;          // 0..127
      vin[j] = *(const float4*)(in + (size_t)(p0+row)*inStride + inOfs + cc + cgrp);
    }
    #pragma unroll
    for (int j = 0; j < 2; ++j){
      int row = (tid + 256*j) >> 3;          // 0..63
      vw[j] = *(const float4*)(W + (size_t)(o0+row)*wStride + cc + cgrp);
    }
    if (cc) __syncthreads();                 // WAR barrier overlaps loads above
    #pragma unroll
    for (int j = 0; j < 4; ++j){
      int row = (tid + 256*j) >> 3, c4 = cgrp;
      float4 v = vin[j];
      if (bnScale){
        v.x = lrelu(v.x*sc4.x + sh4.x); v.y = lrelu(v.y*sc4.y + sh4.y);
        v.z = lrelu(v.z*sc4.z + sh4.z); v.w = lrelu(v.w*sc4.w + sh4.w);
      }
      As[(c4+0)*AS_STRIDE+SKEW(c4+0)+row]=v.x; As[(c4+1)*AS_STRIDE+SKEW(c4+1)+row]=v.y;
      As[(c4+2)*AS_STRIDE+SKEW(c4+2)+row]=v.z; As[(c4+3)*AS_STRIDE+SKEW(c4+3)+row]=v.w;
    }
    #pragma unroll
    for (int j = 0; j < 2; ++j){
      int row = (tid + 256*j) >> 3, c4 = cgrp;
      float4 v = vw[j];
      Ws[(c4+0)*WS_STRIDE+SKEW(c4+0)+row]=v.x; Ws[(c4+1)*WS_STRIDE+SKEW(c4+1)+row]=v.y;
      Ws[(c4+2)*WS_STRIDE+SKEW(c4+2)+row]=v.z; Ws[(c4+3)*WS_STRIDE+SKEW(c4+3)+row]=v.w;
    }
    __syncthreads();
    for (int c = 0; c < 32; ++c){
      const float* arow = &As[c*AS_STRIDE + SKEW(c)];
      const float* brow = &Ws[c*WS_STRIDE + SKEW(c)];
      float4 a0 = *(const float4*)&arow[psub];
      float4 a1 = *(const float4*)&arow[psub + 4];
      float4 bb = *(const float4*)&brow[osub];
      float av[8] = {a0.x,a0.y,a0.z,a0.w,a1.x,a1.y,a1.z,a1.w};
      float bv[4] = {bb.x,bb.y,bb.z,bb.w};
      #pragma unroll
      for (int i = 0; i < 8; ++i)
        #pragma unroll
        for (int j = 0; j < 4; ++j)
          acc[i][j] += av[i]*bv[j];
    }
  }
  int bIdx = p0 >> 12;
  float bb0=0.f, bb1=0.f, bb2=0.f, bb3=0.f;
  if (bias){
    bb0 = bias[bIdx*O + o0 + osub + 0];
    bb1 = bias[bIdx*O + o0 + osub + 1];
    bb2 = bias[bIdx*O + o0 + osub + 2];
    bb3 = bias[bIdx*O + o0 + osub + 3];
  }
  #pragma unroll
  for (int i = 0; i < 8; ++i){
    float4 w;
    w.x = acc[i][0]+bb0; w.y = acc[i][1]+bb1; w.z = acc[i][2]+bb2; w.w = acc[i][3]+bb3;
    *(float4*)(out + (size_t)(p0+psub+i)*outStride + o0 + osub) = w;
  }
}

// ---- point-major matmul, 64p x 64o tile, 4x4 acc/thread (conv6/conv7).
// 32-c staging chunks: LDS 17.9 KB -> 4+ blocks/CU. Same ascending-c
// per-element FMA chain -> bit-identical outputs.
__global__ void __launch_bounds__(256, 2)
mm64_kernel(const float* __restrict__ in, int inStride, int inOfs,
            const float* __restrict__ W, int wStride,
            float* __restrict__ out, int outStride,
            int O, int I,
            const float* __restrict__ bnScale, const float* __restrict__ bnShift){
  __shared__ float As[32*WS_STRIDE + 64];
  __shared__ float Ws[32*WS_STRIDE + 64];
  int tid = threadIdx.x;
  int p0 = blockIdx.x*64, o0 = blockIdx.y*64;
  int psub = (tid >> 4)*4, osub = (tid & 15)*4;
  int cgrp = (tid & 7)*4;
  float acc[4][4] = {};
  for (int cc = 0; cc < I; cc += 32){
    float4 sc4 = make_float4(1.f,1.f,1.f,1.f), sh4 = make_float4(0.f,0.f,0.f,0.f);
    if (bnScale){
      sc4 = *(const float4*)(bnScale + cc + cgrp);
      sh4 = *(const float4*)(bnShift + cc + cgrp);
    }
    float4 vin[2], vw[2];
    #pragma unroll
    for (int j = 0; j < 2; ++j){
      int row = (tid + 256*j) >> 3;     // 0..63
      vin[j] = *(const float4*)(in + (size_t)(p0+row)*inStride + inOfs + cc + cgrp);
      vw[j]  = *(const float4*)(W + (size_t)(o0+row)*wStride + cc + cgrp);
    }
    if (cc) __syncthreads();            // WAR barrier overlaps loads above
    #pragma unroll
    for (int j = 0; j < 2; ++j){
      int row = (tid + 256*j) >> 3, c4 = cgrp;
      float4 v = vin[j];
      if (bnScale){
        v.x = lrelu(v.x*sc4.x + sh4.x); v.y = lrelu(v.y*sc4.y + sh4.y);
        v.z = lrelu(v.z*sc4.z + sh4.z); v.w = lrelu(v.w*sc4.w + sh4.w);
      }
      As[(c4+0)*WS_STRIDE+SKEW(c4+0)+row]=v.x; As[(c4+1)*WS_STRIDE+SKEW(c4+1)+row]=v.y;
      As[(c4+2)*WS_STRIDE+SKEW(c4+2)+row]=v.z; As[(c4+3)*WS_STRIDE+SKEW(c4+3)+row]=v.w;
      float4 w = vw[j];
      Ws[(c4+0)*WS_STRIDE+SKEW(c4+0)+row]=w.x; Ws[(c4+1)*WS_STRIDE+SKEW(c4+1)+row]=w.y;
      Ws[(c4+2)*WS_STRIDE+SKEW(c4+2)+row]=w.z; Ws[(c4+3)*WS_STRIDE+SKEW(c4+3)+row]=w.w;
    }
    __syncthreads();
    for (int c = 0; c < 32; ++c){
      const float* arow = &As[c*WS_STRIDE + SKEW(c)];
      const float* brow = &Ws[c*WS_STRIDE + SKEW(c)];
      float4 a0 = *(const float4*)&arow[psub];
      float4 bb = *(const float4*)&brow[osub];
      float av[4] = {a0.x,a0.y,a0.z,a0.w};
      float bv[4] = {bb.x,bb.y,bb.z,bb.w};
      #pragma unroll
      for (int i = 0; i < 4; ++i)
        #pragma unroll
        for (int j = 0; j < 4; ++j)
          acc[i][j] += av[i]*bv[j];
    }
  }
  #pragma unroll
  for (int i = 0; i < 4; ++i){
    float4 w;
    w.x = acc[i][0]; w.y = acc[i][1]; w.z = acc[i][2]; w.w = acc[i][3];
    *(float4*)(out + (size_t)(p0+psub+i)*outStride + o0 + osub) = w;
  }
}

// ---- conv4 FUSED with stats: computes the 128x128 r4 tile in registers, then
// reduces in-block to per-channel sum/sumsq partials + per-(tile,ch) max/min.
// r4 is NEVER materialized (saves its 33.5 MB write + 33.5 MB stats re-read).
__global__ void __launch_bounds__(256, 2)
conv4stats_kernel(const float* __restrict__ xcat, const float* __restrict__ W4,
                  float* __restrict__ psum, float* __restrict__ psumsq,
                  float* __restrict__ pmax, float* __restrict__ pmin){
  __shared__ float As[64*AS_STRIDE + 64];
  __shared__ float Ws[64*AS_STRIDE + 64];
  int tid = threadIdx.x;
  int p0 = blockIdx.x*128, o0 = blockIdx.y*128;
  int pA = (tid >> 4)*4, oB = (tid & 15)*4;
  int cgrp = (tid & 15)*4;
  float4 vin[8], vw[8];
  #pragma unroll
  for (int j = 0; j < 8; ++j){
    int row = (tid + 256*j) >> 4;
    vin[j] = *(const float4*)(xcat + (size_t)(p0+row)*192 + 128 + cgrp);
    vw[j]  = *(const float4*)(W4 + (size_t)(o0+row)*64 + cgrp);
  }
  #pragma unroll
  for (int j = 0; j < 8; ++j){
    int row = (tid + 256*j) >> 4, c4 = cgrp;
    float4 v = vin[j];
    As[(c4+0)*AS_STRIDE+SKEW(c4+0)+row]=v.x; As[(c4+1)*AS_STRIDE+SKEW(c4+1)+row]=v.y;
    As[(c4+2)*AS_STRIDE+SKEW(c4+2)+row]=v.z; As[(c4+3)*AS_STRIDE+SKEW(c4+3)+row]=v.w;
    float4 w = vw[j];
    Ws[(c4+0)*AS_STRIDE+SKEW(c4+0)+row]=w.x; Ws[(c4+1)*AS_STRIDE+SKEW(c4+1)+row]=w.y;
    Ws[(c4+2)*AS_STRIDE+SKEW(c4+2)+row]=w.z; Ws[(c4+3)*AS_STRIDE+SKEW(c4+3)+row]=w.w;
  }
  __syncthreads();
  float acc[8][8] = {};
  for (int c = 0; c < 64; ++c){
    const float* arow = &As[c*AS_STRIDE + SKEW(c)];
    const float* brow = &Ws[c*AS_STRIDE + SKEW(c)];
    float4 a0 = *(const float4*)&arow[pA];
    float4 a1 = *(const float4*)&arow[pA + 64];
    float4 b0 = *(const float4*)&brow[oB];
    float4 b1 = *(const float4*)&brow[oB + 64];
    float av[8] = {a0.x,a0.y,a0.z,a0.w,a1.x,a1.y,a1.z,a1.w};
    float bv[8] = {b0.x,b0.y,b0.z,b0.w,b1.x,b1.y,b1.z,b1.w};
    #pragma unroll
    for (int i = 0; i < 8; ++i)
      #pragma unroll
      for (int j = 0; j < 8; ++j)
        acc[i][j] += av[i]*bv[j];
  }
  // per-thread column partials over its 8 rows (fixed order i=0..7)
  float cs[8], cq[8], cmx[8], cmn[8];
  #pragma unroll
  for (int j = 0; j < 8; ++j){
    float s = 0.f, q = 0.f, mx = -INFINITY, mn = INFINITY;
    #pragma unroll
    for (int i = 0; i < 8; ++i){
      float v = acc[i][j];
      s += v; q += v*v; mx = fmaxf(mx, v); mn = fminf(mn, v);
    }
    cs[j]=s; cq[j]=q; cmx[j]=mx; cmn[j]=mn;
  }
  __syncthreads();   // done reading As/Ws; reuse as scratch
  int r = tid >> 4;
  #pragma unroll
  for (int j = 0; j < 8; ++j){
    int col = (j < 4) ? (oB + j) : (64 + oB + (j-4));
    As[r*128 + col]        = cs[j];
    As[2048 + r*128 + col] = cq[j];
    Ws[r*128 + col]        = cmx[j];
    Ws[2048 + r*128 + col] = cmn[j];
  }
  __syncthreads();
  if (tid < 128){
    float ts = 0.f, tq = 0.f, tm = -INFINITY, tn = INFINITY;
    for (int rr = 0; rr < 16; ++rr){
      ts += As[rr*128 + tid];
      tq += As[2048 + rr*128 + tid];
      tm = fmaxf(tm, Ws[rr*128 + tid]);
      tn = fminf(tn, Ws[2048 + rr*128 + tid]);
    }
    size_t slot = (size_t)blockIdx.x*512 + o0 + tid;
    psum[slot] = ts; psumsq[slot] = tq; pmax[slot] = tm; pmin[slot] = tn;
  }
}

// lrelu(s*v+t) monotone in v: use max if s>=0 else min  (32 tiles per batch)
__global__ void x6v_kernel(const float* __restrict__ pmax, const float* __restrict__ pmin,
                           const float* __restrict__ scale, const float* __restrict__ shift,
                           float* __restrict__ x6v){
  int t = blockIdx.x*256 + threadIdx.x;
  int b = t >> 9, o = t & 511;
  float mx = -INFINITY, mn = INFINITY;
  for (int pt = b*32; pt < b*32+32; ++pt){
    mx = fmaxf(mx, pmax[(size_t)pt*512 + o]);
    mn = fminf(mn, pmin[(size_t)pt*512 + o]);
  }
  float s = scale[o];
  float v = (s >= 0.f) ? mx : mn;
  x6v[t] = lrelu(s*v + shift[o]);
}

// bias5[b,o] = sum_c W5[o, 192+c] * x6v[b,c]   (the broadcast part of the concat)
__global__ void bias5_kernel(const float* __restrict__ W5, const float* __restrict__ x6v,
                             float* __restrict__ b5){
  __shared__ float xl[512];
  int tid = threadIdx.x;
  int t = blockIdx.x*256 + tid;
  int b = t >> 9, o = t & 511;
  for (int i = tid; i < 512; i += 256) xl[i] = x6v[(b<<9) + i];
  __syncthreads();
  const float* wr = W5 + (size_t)o*704 + 192;
  float acc = 0.f;
  for (int c = 0; c < 512; ++c) acc += wr[c]*xl[c];
  b5[t] = acc;
}

// ---- conv8 (128->2) + bias over raw r7 with BN7+lrelu applied inline
__global__ void conv8_kernel(const float* __restrict__ r7, const float* __restrict__ W8,
                             const float* __restrict__ bias8,
                             const float* __restrict__ scale, const float* __restrict__ shift,
                             float* __restrict__ out){
  __shared__ float Wl[256];
  __shared__ float scl[128], shl[128];
  int tid = threadIdx.x;
  Wl[tid] = W8[tid];
  if (tid < 128){ scl[tid] = scale[tid]; shl[tid] = shift[tid]; }
  __syncthreads();
  int p = blockIdx.x*256 + tid;
  int b = p >> 12, n = p & 4095;
  const float4* row = (const float4*)(r7 + (size_t)p*128);
  float a0 = 0.f, a1 = 0.f;
  #pragma unroll
  for (int i = 0; i < 32; ++i){
    float4 v = row[i];
    v.x = lrelu(v.x*scl[i*4+0] + shl[i*4+0]);
    v.y = lrelu(v.y*scl[i*4+1] + shl[i*4+1]);
    v.z = lrelu(v.z*scl[i*4+2] + shl[i*4+2]);
    v.w = lrelu(v.w*scl[i*4+3] + shl[i*4+3]);
    a0 += v.x*Wl[i*4] + v.y*Wl[i*4+1] + v.z*Wl[i*4+2] + v.w*Wl[i*4+3];
    a1 += v.x*Wl[128+i*4] + v.y*Wl[128+i*4+1] + v.z*Wl[128+i*4+2] + v.w*Wl[128+i*4+3];
  }
  out[(size_t)(b*2+0)*NN + n] = a0 + bias8[0];
  out[(size_t)(b*2+1)*NN + n] = a1 + bias8[1];
}

extern "C" void kernel_launch(void* const* d_in, const int* in_sizes, int n_in,
                              void* d_out, int out_size, void* d_ws, size_t ws_size,
                              hipStream_t stream){
  const float* x     = (const float*)d_in[0];
  const float* W1    = (const float*)d_in[1];
  const float* W2    = (const float*)d_in[2];
  const float* W3    = (const float*)d_in[3];
  const float* W4    = (const float*)d_in[4];
  const float* W5    = (const float*)d_in[5];
  const float* W6    = (const float*)d_in[6];
  const float* W7    = (const float*)d_in[7];
  const float* W8    = (const float*)d_in[8];
  const float* bias8 = (const float*)d_in[9];
  const float* gamma[8]; const float* beta[8];
  for (int i = 1; i <= 7; ++i){
    gamma[i] = (const float*)d_in[10 + 2*(i-1)];
    beta[i]  = (const float*)d_in[11 + 2*(i-1)];
  }
  float* out = (float*)d_out;

  float* ws = (float*)d_ws;
  size_t off = 0;
  float* xcat  = ws + off; off += (size_t)NPT*192;   // x1|x2|x3 packed, stride 192
  float* U     = ws + off; off += (size_t)NPT*64;
  float* T     = ws + off; off += (size_t)NPT*64;
  float* xx    = ws + off; off += NPT;
  int*   idx   = (int*)(ws + off); off += (size_t)NPT*KK;
  float* psum  = ws + off; off += 128*512;
  float* psumsq= ws + off; off += 128*512;
  float* pmax  = ws + off; off += 128*512;
  float* pmin  = ws + off; off += 128*512;
  float* scale = ws + off; off += 512;
  float* shift = ws + off; off += 512;
  float* x6v   = ws + off; off += 2048;
  float* b5    = ws + off; off += 2048;
  float* big   = ws + off;   // time-shared: dist (knn) / vmax|vmin (gather) / r5|r6|r7
  float* dist  = big;                               // 16.8M floats (one batch)
  float* vmaxB = big;                               // NPT*64, live only between knn rounds
  float* vminB = big + (size_t)NPT*64;
  float* r5    = big;
  float* r6    = big + (size_t)NPT*512;
  float* r7    = big + (size_t)NPT*512 + (size_t)NPT*256;
  // gmax overlays U|T (dead during knn): 4096 rows x 512 groups u32 = 2M words
  unsigned* gmaxU = (unsigned*)U;

  // ---- stage 1: conv1 + BN(train stats) + lrelu -> x1 (xcat[:,0:64])
  conv1_kernel<<<NPT/4, 256, 0, stream>>>(x, W1, xcat);
  stats_pm_kernel<<<dim3(1,64), 256, 0, stream>>>(xcat, 192, 0, psum, psumsq, 64);
  bn_finalize_kernel<<<1, 64, 0, stream>>>(psum, psumsq, 64, gamma[1], beta[1], scale, shift, 1.f/16384.f, 64);
  apply_bn_kernel<<<NPT*64/256, 256, 0, stream>>>(xcat, 192, 0, 6, scale, shift);

  // ---- knn on x1 (triangular dist+gmax; filtered exact top-20)
  xx_kernel<<<NPT/256, 256, 0, stream>>>(xcat, 192, 0, xx);
  for (int b = 0; b < BB; ++b){
    dist_kernel<<<dim3(32,32), 256, 0, stream>>>(xcat, 0, xx, dist, gmaxU, b);
    topk_kernel<<<NN/4, 256, 0, stream>>>(dist, gmaxU, idx + (size_t)b*NN*KK);
  }

  // ---- stage 2: edge-conv (W2): single gather pass (stats + vmax/vmin), then elementwise
  ut_kernel<<<NPT/4, 256, 0, stream>>>(xcat, 0, W2, U, T);
  gather_kernel<<<256, 256, 0, stream>>>(U, T, idx, psum, psumsq, vmaxB, vminB);
  bn_finalize_kernel<<<1, 64, 0, stream>>>(psum, psumsq, 256, gamma[2], beta[2], scale, shift, 1.f/327680.f, 64);
  gapply_kernel<<<NPT*64/256, 256, 0, stream>>>(vmaxB, vminB, scale, shift, xcat, 64);

  // ---- knn on x2
  xx_kernel<<<NPT/256, 256, 0, stream>>>(xcat, 192, 64, xx);
  for (int b = 0; b < BB; ++b){
    dist_kernel<<<dim3(32,32), 256, 0, stream>>>(xcat, 64, xx, dist, gmaxU, b);
    topk_kernel<<<NN/4, 256, 0, stream>>>(dist, gmaxU, idx + (size_t)b*NN*KK);
  }

  // ---- stage 3: edge-conv (W3) -> x3
  ut_kernel<<<NPT/4, 256, 0, stream>>>(xcat, 64, W3, U, T);
  gather_kernel<<<256, 256, 0, stream>>>(U, T, idx, psum, psumsq, vmaxB, vminB);
  bn_finalize_kernel<<<1, 64, 0, stream>>>(psum, psumsq, 256, gamma[3], beta[3], scale, shift, 1.f/327680.f, 64);
  gapply_kernel<<<NPT*64/256, 256, 0, stream>>>(vmaxB, vminB, scale, shift, xcat, 128);

  // ---- stage 4: conv4 fused with stats (r4 never materialized)
  conv4stats_kernel<<<dim3(NPT/128, 4), 256, 0, stream>>>(xcat, W4, psum, psumsq, pmax, pmin);
  bn_finalize_kernel<<<1, 512, 0, stream>>>(psum, psumsq, 128, gamma[4], beta[4], scale, shift, 1.f/16384.f, 512);
  x6v_kernel<<<8, 256, 0, stream>>>(pmax, pmin, scale, shift, x6v);
  bias5_kernel<<<8, 256, 0, stream>>>(W5, x6v, b5);

  // ---- stage 5: conv5 (704->512) via mm_kernel 64-o tiles: grid 1024 blocks
  // (was mm128 512 blocks = 2/CU grid-limited); 32-c chunks -> LDS 26 KB.
  mm_kernel<<<dim3(NPT/128, 8), 256, 0, stream>>>(xcat, 192, 0, W5, 704, r5, 512, b5, 512, 192, nullptr, nullptr);
  stats_pm_kernel<<<dim3(8,64), 256, 0, stream>>>(r5, 512, 0, psum, psumsq, 512);
  bn_finalize_kernel<<<1, 512, 0, stream>>>(psum, psumsq, 64, gamma[5], beta[5], scale, shift, 1.f/16384.f, 512);

  // ---- stage 6: conv6 (512->256), BN5+lrelu on load; r6 stays RAW.
  // mm64 64x64 tiles: grid (256,4) = 1024 blocks, LDS 17.9 KB -> 4 blocks/CU.
  mm64_kernel<<<dim3(NPT/64, 4), 256, 0, stream>>>(r5, 512, 0, W6, 512, r6, 256, 256, 512, scale, shift);
  stats_pm_kernel<<<dim3(4,64), 256, 0, stream>>>(r6, 256, 0, psum, psumsq, 256);
  bn_finalize_kernel<<<1, 256, 0, stream>>>(psum, psumsq, 64, gamma[6], beta[6], scale, shift, 1.f/16384.f, 256);

  // ---- stage 7: conv7 (256->128), BN6+lrelu on load; r7 stays RAW.
  mm64_kernel<<<dim3(NPT/64, 2), 256, 0, stream>>>(r6, 256, 0, W7, 256, r7, 128, 128, 256, scale, shift);
  stats_pm_kernel<<<dim3(2,64), 256, 0, stream>>>(r7, 128, 0, psum, psumsq, 128);
  bn_finalize_kernel<<<1, 128, 0, stream>>>(psum, psumsq, 64, gamma[7], beta[7], scale, shift, 1.f/16384.f, 128);

  // ---- stage 8: conv8 (128->2) + bias, BN7+lrelu applied inline
  conv8_kernel<<<NPT/256, 256, 0, stream>>>(r7, W8, bias8, scale, shift, out);
}

// Round 12
// 1083.672 us; speedup vs baseline: 1.7232x; 1.0049x over previous
//
#include <hip/hip_runtime.h>
#include <math.h>

#define NN 4096
#define BB 4
#define NPT (NN*BB)
#define KK 20
#define EPSB 1e-5f

#define AS_STRIDE 132   // 128-point c-row, padded
#define WS_STRIDE 68    // 64-col c-row, padded
// Non-wrapping per-channel skew: staging writes 2-way (free), reads clean,
// all offsets multiples of 4 floats so float4 reads stay 16B-aligned.
#define SKEW(c) ((((((c)>>2)&7))<<2) + (((c)>>5)*28))

__device__ __forceinline__ float lrelu(float x){ return x >= 0.f ? x : 0.2f*x; }

// monotone float->uint key: order(key) == order(float)
__device__ __forceinline__ unsigned fkey(float x){
  unsigned u = __float_as_uint(x);
  return u ^ (unsigned)(((int)u >> 31) | 0x80000000);
}

// ---- stage 1: conv1 (3->64), writes raw into xcat[:, 0:64] (point-major, row stride 192)
__global__ void conv1_kernel(const float* __restrict__ x, const float* __restrict__ W1,
                             float* __restrict__ xcat){
  __shared__ float Wl[192];
  int tid = threadIdx.x;
  if (tid < 192) Wl[tid] = W1[tid];
  __syncthreads();
  int p = blockIdx.x*4 + (tid >> 6);
  int o = tid & 63;
  int b = p >> 12, n = p & 4095;
  const float* xb = x + (size_t)b*3*NN + n;
  float acc = Wl[o*3+0]*xb[0] + Wl[o*3+1]*xb[NN] + Wl[o*3+2]*xb[2*NN];
  xcat[(size_t)p*192 + o] = acc;
}

// ---- per-channel partial stats for point-major (NPT, C) buffer; deterministic slots
__global__ void stats_pm_kernel(const float* __restrict__ buf, int stride, int ofs,
                                float* __restrict__ psum, float* __restrict__ psumsq, int C){
  int tid = threadIdx.x;
  int lane = tid & 63, g = tid >> 6;
  int o = blockIdx.x*64 + lane;
  int p0 = blockIdx.y*256 + g*64;
  float s = 0.f, ss = 0.f;
  for (int i = 0; i < 64; ++i){
    float v = buf[(size_t)(p0+i)*stride + ofs + o];
    s += v; ss += v*v;
  }
  __shared__ float rs[4][64], rss[4][64];
  rs[g][lane] = s; rss[g][lane] = ss;
  __syncthreads();
  if (g == 0){
    s  = rs[0][lane]+rs[1][lane]+rs[2][lane]+rs[3][lane];
    ss = rss[0][lane]+rss[1][lane]+rss[2][lane]+rss[3][lane];
    psum[(size_t)blockIdx.y*C + o] = s;
    psumsq[(size_t)blockIdx.y*C + o] = ss;
  }
}

// deterministic finalize: serial sum over nparts partials per channel
__global__ void bn_finalize_kernel(const float* __restrict__ psum, const float* __restrict__ psumsq,
                                   int nparts,
                                   const float* __restrict__ gamma, const float* __restrict__ beta,
                                   float* __restrict__ scale, float* __restrict__ shift,
                                   float invcnt, int C){
  int o = threadIdx.x + blockIdx.x*blockDim.x;
  if (o >= C) return;
  float s = 0.f, ss = 0.f;
  for (int i = 0; i < nparts; ++i){
    s  += psum[(size_t)i*C + o];
    ss += psumsq[(size_t)i*C + o];
  }
  float m = s*invcnt;
  float v = ss*invcnt - m*m;
  v = fmaxf(v, 0.f);
  float sc = gamma[o] * rsqrtf(v + EPSB);
  scale[o] = sc;
  shift[o] = beta[o] - m*sc;
}

__global__ void apply_bn_kernel(float* __restrict__ buf, int stride, int ofs, int log2C,
                                const float* __restrict__ scale, const float* __restrict__ shift){
  int i = blockIdx.x*256 + threadIdx.x;
  int o = i & ((1<<log2C)-1);
  int p = i >> log2C;
  size_t a = (size_t)p*stride + ofs + o;
  float e = buf[a]*scale[o] + shift[o];
  buf[a] = lrelu(e);
}

// ---- ||x||^2 per point (64 features)
__global__ void xx_kernel(const float* __restrict__ xcat, int stride, int ofs,
                          float* __restrict__ xx){
  int p = blockIdx.x*256 + threadIdx.x;
  const float4* r = (const float4*)(xcat + (size_t)p*stride + ofs);
  float s = 0.f;
  #pragma unroll
  for (int i = 0; i < 16; ++i){ float4 v = r[i]; s += v.x*v.x + v.y*v.y + v.z*v.z + v.w*v.w; }
  xx[p] = s;
}

// ---- dist: TRIANGULAR 128n x 128m tiles (by<=bx) + mirror write + gmax.
// 32-c staging chunks (LDS 34.3 KB -> 4 blocks/CU at (256,2); round-10's
// proven recipe — round-1's regression was the (256,4) VGPR cap, not chunking).
// Per-element FMA chain is still one ascending-c += sequence across the two
// chunks -> bit-identical dist values and gmax keys.
__global__ void __launch_bounds__(256, 2)
dist_kernel(const float* __restrict__ xcat, int ofs,
            const float* __restrict__ xx, float* __restrict__ dist,
            unsigned* __restrict__ gmaxp, int b){
  int bx = blockIdx.x, by = blockIdx.y;
  if (by > bx) return;                 // lower triangle filled by mirror
  __shared__ float As[32*AS_STRIDE + 64];
  __shared__ float Bs[32*AS_STRIDE + 64];
  int tid = threadIdx.x;
  int n0 = by*128, m0 = bx*128;        // row tile <= col tile
  const float* base = xcat + (size_t)b*NN*192 + ofs;
  int pA = (tid >> 4)*4, oB = (tid & 15)*4;
  int cgrp = (tid & 7)*4;
  float acc[8][8] = {};   // i: 0-3 rows pA+i, 4-7 rows pA+64+(i-4); j likewise cols
  for (int h = 0; h < 2; ++h){
    int cb = h*32;
    float4 vin[4], vw[4];
    #pragma unroll
    for (int j = 0; j < 4; ++j){
      int row = (tid + 256*j) >> 3;          // 0..127
      vin[j] = *(const float4*)(base + (size_t)(n0+row)*192 + cb + cgrp);
      vw[j]  = *(const float4*)(base + (size_t)(m0+row)*192 + cb + cgrp);
    }
    if (h) __syncthreads();                  // WAR barrier overlaps loads above
    #pragma unroll
    for (int j = 0; j < 4; ++j){
      int row = (tid + 256*j) >> 3, c4 = cgrp;
      float4 v = vin[j];
      As[(c4+0)*AS_STRIDE+SKEW(c4+0)+row]=v.x; As[(c4+1)*AS_STRIDE+SKEW(c4+1)+row]=v.y;
      As[(c4+2)*AS_STRIDE+SKEW(c4+2)+row]=v.z; As[(c4+3)*AS_STRIDE+SKEW(c4+3)+row]=v.w;
      float4 w = vw[j];
      Bs[(c4+0)*AS_STRIDE+SKEW(c4+0)+row]=w.x; Bs[(c4+1)*AS_STRIDE+SKEW(c4+1)+row]=w.y;
      Bs[(c4+2)*AS_STRIDE+SKEW(c4+2)+row]=w.z; Bs[(c4+3)*AS_STRIDE+SKEW(c4+3)+row]=w.w;
    }
    __syncthreads();                         // RAW
    for (int c = 0; c < 32; ++c){
      const float* arow = &As[c*AS_STRIDE + SKEW(c)];
      const float* brow = &Bs[c*AS_STRIDE + SKEW(c)];
      float4 a0 = *(const float4*)&arow[pA];
      float4 a1 = *(const float4*)&arow[pA + 64];
      float4 b0 = *(const float4*)&brow[oB];
      float4 b1 = *(const float4*)&brow[oB + 64];
      float av[8] = {a0.x,a0.y,a0.z,a0.w,a1.x,a1.y,a1.z,a1.w};
      float bv[8] = {b0.x,b0.y,b0.z,b0.w,b1.x,b1.y,b1.z,b1.w};
      #pragma unroll
      for (int i = 0; i < 8; ++i)
        #pragma unroll
        for (int j = 0; j < 8; ++j)
          acc[i][j] += av[i]*bv[j];
    }
  }
  float xmv[8], xnv[8];
  #pragma unroll
  for (int j = 0; j < 4; ++j){
    xmv[j]   = xx[b*NN + m0 + oB + j];
    xmv[4+j] = xx[b*NN + m0 + 64 + oB + j];
    xnv[j]   = xx[b*NN + n0 + pA + j];
    xnv[4+j] = xx[b*NN + n0 + 64 + pA + j];
  }
  #pragma unroll
  for (int h = 0; h < 2; ++h){
    #pragma unroll
    for (int i = 0; i < 4; ++i){
      int row = n0 + h*64 + pA + i;
      float xn = xnv[h*4 + i];
      int ai = h*4 + i;
      float4 w0, w1;
      w0.x = 2.f*acc[ai][0] - xn - xmv[0]; w0.y = 2.f*acc[ai][1] - xn - xmv[1];
      w0.z = 2.f*acc[ai][2] - xn - xmv[2]; w0.w = 2.f*acc[ai][3] - xn - xmv[3];
      w1.x = 2.f*acc[ai][4] - xn - xmv[4]; w1.y = 2.f*acc[ai][5] - xn - xmv[5];
      w1.z = 2.f*acc[ai][6] - xn - xmv[6]; w1.w = 2.f*acc[ai][7] - xn - xmv[7];
      float* drow = dist + (size_t)row*NN + m0;
      *(float4*)(drow + oB) = w0;
      *(float4*)(drow + 64 + oB) = w1;
      unsigned gm = fkey(w0.x), t;
      t = fkey(w0.y); if (t > gm) gm = t;
      t = fkey(w0.z); if (t > gm) gm = t;
      t = fkey(w0.w); if (t > gm) gm = t;
      t = fkey(w1.x); if (t > gm) gm = t;
      t = fkey(w1.y); if (t > gm) gm = t;
      t = fkey(w1.z); if (t > gm) gm = t;
      t = fkey(w1.w); if (t > gm) gm = t;
      gmaxp[(size_t)row*512 + (bx<<4) + (oB>>2)] = gm;
    }
  }
  if (bx != by){
    // mirror: element (m,n) = ((2a - xx[m]) - xx[n]); float4 along contiguous n
    #pragma unroll
    for (int jh = 0; jh < 2; ++jh){
      #pragma unroll
      for (int jj = 0; jj < 4; ++jj){
        int j = jh*4 + jj;
        float xm = xmv[j];
        float4 lo, hi;
        lo.x = 2.f*acc[0][j] - xm - xnv[0];
        lo.y = 2.f*acc[1][j] - xm - xnv[1];
        lo.z = 2.f*acc[2][j] - xm - xnv[2];
        lo.w = 2.f*acc[3][j] - xm - xnv[3];
        hi.x = 2.f*acc[4][j] - xm - xnv[4];
        hi.y = 2.f*acc[5][j] - xm - xnv[5];
        hi.z = 2.f*acc[6][j] - xm - xnv[6];
        hi.w = 2.f*acc[7][j] - xm - xnv[7];
        int mrow = m0 + jh*64 + oB + jj;
        float* drow = dist + (size_t)mrow*NN + n0;
        *(float4*)(drow + pA) = lo;
        *(float4*)(drow + 64 + pA) = hi;
        unsigned gm = fkey(lo.x), t;
        t = fkey(lo.y); if (t > gm) gm = t;
        t = fkey(lo.z); if (t > gm) gm = t;
        t = fkey(lo.w); if (t > gm) gm = t;
        t = fkey(hi.x); if (t > gm) gm = t;
        t = fkey(hi.y); if (t > gm) gm = t;
        t = fkey(hi.z); if (t > gm) gm = t;
        t = fkey(hi.w); if (t > gm) gm = t;
        gmaxp[(size_t)mrow*512 + (by<<4) + (pA>>2)] = gm;
      }
    }
  }
}

// ---- topk v3b: group-max prefilter + exact selection. One wave per row.
// T = conservative threshold from a SHORTENED binary radix over the 512 group
// maxima: scan bits 31..16 only, with early exit once the passing-group count
// (20-need)+|act| <= 44. Any prefix-truncated T satisfies T <= T_exact <= v20
// (>=20 groups have gmax >= T), so the value-filter key>=T keeps every top-20
// value incl. ties -> selection stays exact. Candidates gathered to per-wave
// LDS; C<=64: 64-lane bitonic sort (value desc, index asc); C>64: exact
// fallback rescans dist directly (independent of the LDS buffer).
__global__ void __launch_bounds__(256)
topk_kernel(const float* __restrict__ dist, const unsigned* __restrict__ gmax,
            int* __restrict__ idxout){
  __shared__ unsigned lv[4][256], li[4][256];
  __shared__ unsigned lcnt[4];
  int wv = threadIdx.x >> 6, lane = threadIdx.x & 63;
  int n = blockIdx.x*4 + wv;
  const unsigned* grow = gmax + (size_t)n*512;
  unsigned g[8];
  #pragma unroll
  for (int j = 0; j < 8; ++j) g[j] = grow[j*64 + lane];
  if (lane == 0) lcnt[wv] = 0u;          // same-wave LDS ops are in-order
  unsigned prefix = 0u, act = 0xFFu; int need = KK; int tot = 512;
  for (int b = 31; b >= 16; --b){
    unsigned m = 0u;
    #pragma unroll
    for (int j = 0; j < 8; ++j) m |= ((g[j] >> b) & 1u) << j;
    unsigned c = (unsigned)__popc(m & act);
    #pragma unroll
    for (int s = 1; s < 64; s <<= 1) c += __shfl_xor(c, s);
    if ((int)c >= need){ act &= m; prefix |= (1u << b); tot = (int)c; }
    else { need -= (int)c; act &= ~m; tot -= (int)c; }
    if (KK - need + tot <= 44) break;    // few enough passing groups: stop
  }
  unsigned T = prefix;                    // conservative (<= exact 20th gmax)
  const float* drow = dist + (size_t)n*NN;
  #pragma unroll
  for (int j = 0; j < 8; ++j){
    if (g[j] >= T){
      int gid = j*64 + lane;
      int cbase = ((gid >> 4) << 7) + ((gid & 15) << 2);
      float4 v0 = *(const float4*)(drow + cbase);
      float4 v1 = *(const float4*)(drow + cbase + 64);
      unsigned k0=fkey(v0.x),k1=fkey(v0.y),k2=fkey(v0.z),k3=fkey(v0.w);
      unsigned k4=fkey(v1.x),k5=fkey(v1.y),k6=fkey(v1.z),k7=fkey(v1.w);
      int q = (k0>=T)+(k1>=T)+(k2>=T)+(k3>=T)+(k4>=T)+(k5>=T)+(k6>=T)+(k7>=T);
      unsigned pos = atomicAdd(&lcnt[wv], (unsigned)q);
      #define PUTC(kx,cofs) if (kx >= T){ if (pos < 256u){ lv[wv][pos]=kx; li[wv][pos]=(unsigned)(cbase+(cofs)); } pos++; }
      PUTC(k0,0) PUTC(k1,1) PUTC(k2,2) PUTC(k3,3)
      PUTC(k4,64) PUTC(k5,65) PUTC(k6,66) PUTC(k7,67)
      #undef PUTC
    }
  }
  unsigned C = lcnt[wv];                  // all wave atomics precede this read
  int* orow = idxout + (size_t)n*KK;
  if (C <= 64u){
    unsigned kv = 0u, ki = 0xFFFFFFFFu;   // dummy key 0 = -inf, never a real dist
    if (lane < (int)C){ kv = lv[wv][lane]; ki = li[wv][lane]; }
    #pragma unroll
    for (int k = 2; k <= 64; k <<= 1){
      #pragma unroll
      for (int j2 = k >> 1; j2 > 0; j2 >>= 1){
        unsigned ov = __shfl_xor(kv, j2);
        unsigned oi = __shfl_xor(ki, j2);
        bool iLower = ((lane & j2) == 0);
        bool dirDesc = ((lane & k) == 0);
        bool mineGr = (kv > ov) || (kv == ov && ki < oi);
        bool keep = dirDesc ? (iLower ? mineGr : !mineGr)
                            : (iLower ? !mineGr : mineGr);
        kv = keep ? kv : ov;
        ki = keep ? ki : oi;
      }
    }
    if (lane < KK) orow[lane] = (int)ki;
  } else {
    // rare exact fallback: rescan qualifying groups, per-lane reg top-20 + merge
    unsigned rv[KK], ri[KK];
    #pragma unroll
    for (int q = 0; q < KK; ++q){ rv[q]=0u; ri[q]=0xFFFFFFFFu; }
    #pragma unroll
    for (int j = 0; j < 8; ++j){
      if (g[j] >= T){
        int gid = j*64 + lane;
        int cbase = ((gid >> 4) << 7) + ((gid & 15) << 2);
        float4 v0 = *(const float4*)(drow + cbase);
        float4 v1 = *(const float4*)(drow + cbase + 64);
        float f0[8] = {v0.x,v0.y,v0.z,v0.w,v1.x,v1.y,v1.z,v1.w};
        #pragma unroll
        for (int t = 0; t < 8; ++t){
          unsigned u = fkey(f0[t]);
          unsigned ix = (unsigned)(cbase + ((t < 4) ? t : (60 + t)));
          bool beat = (u > rv[KK-1]) || (u == rv[KK-1] && ix < ri[KK-1]);
          if (u >= T && beat){
            unsigned pv = u, pi = ix;
            #pragma unroll
            for (int p = 0; p < KK; ++p){
              bool keep2 = (rv[p] > pv) || (rv[p] == pv && ri[p] < pi);
              unsigned nv = keep2 ? rv[p] : pv;
              unsigned ni = keep2 ? ri[p] : pi;
              pv = keep2 ? pv : rv[p];
              pi = keep2 ? pi : ri[p];
              rv[p] = nv; ri[p] = ni;
            }
          }
        }
      }
    }
    for (int q = 0; q < KK; ++q){
      unsigned bv = rv[0], bi = ri[0];
      #pragma unroll
      for (int s = 1; s < 64; s <<= 1){
        unsigned ov = __shfl_xor(bv, s);
        unsigned oi = __shfl_xor(bi, s);
        bool take = (ov > bv) || (ov == bv && oi < bi);
        bv = take ? ov : bv;
        bi = take ? oi : bi;
      }
      if (rv[0] == bv && ri[0] == bi){
        #pragma unroll
        for (int p = 0; p < KK-1; ++p){ rv[p] = rv[p+1]; ri[p] = ri[p+1]; }
        rv[KK-1] = 0u; ri[KK-1] = 0xFFFFFFFFu;
      }
      if (lane == 0) orow[q] = (int)bi;
    }
  }
}

// ---- U = W[:, :64] * x ; T = (W[:,64:] - W[:, :64]) * x  (per point, point-major out)
__global__ void ut_kernel(const float* __restrict__ xcat, int ofs, const float* __restrict__ W,
                          float* __restrict__ U, float* __restrict__ T){
  __shared__ float Wl[64*129];
  int tid = threadIdx.x;
  for (int i = tid; i < 64*128; i += 256){
    int o = i >> 7, c = i & 127;
    Wl[o*129 + c] = W[i];
  }
  __syncthreads();
  int g = tid >> 6, lane = tid & 63;
  int p = blockIdx.x*4 + g;
  float xv = xcat[(size_t)p*192 + ofs + lane];
  const float* wr = Wl + lane*129;
  float u = 0.f, t = 0.f;
  for (int c = 0; c < 64; ++c){
    float xc = __shfl(xv, c);
    float wa = wr[c], wb = wr[64+c];
    u += wa*xc;
    t += (wb - wa)*xc;
  }
  U[(size_t)p*64 + lane] = u;
  T[(size_t)p*64 + lane] = t;
}

// ---- ONE gather pass: v = U[j]+T[n] over k -> per-channel partial sum/sumsq
// (deterministic slots) AND per-(point,ch) vmax/vmin (lrelu-monotone max trick).
__global__ void gather_kernel(const float* __restrict__ U, const float* __restrict__ T,
                              const int* __restrict__ idx,
                              float* __restrict__ psum, float* __restrict__ psumsq,
                              float* __restrict__ vmax, float* __restrict__ vmin){
  int tid = threadIdx.x;
  int g = tid >> 6, lane = tid & 63;
  int p0 = blockIdx.x*64 + g*16;
  float s = 0.f, ss = 0.f;
  for (int pi = 0; pi < 16; ++pi){
    int p = p0 + pi;
    int base = (p >> 12) << 12;
    float t = T[(size_t)p*64 + lane];
    const int* ir = idx + (size_t)p*KK;
    float mx = -INFINITY, mn = INFINITY;
    for (int k = 0; k < KK; ++k){
      int j = ir[k];
      float v = U[(size_t)(base + j)*64 + lane] + t;
      s += v; ss += v*v;
      mx = fmaxf(mx, v); mn = fminf(mn, v);
    }
    vmax[(size_t)p*64 + lane] = mx;
    vmin[(size_t)p*64 + lane] = mn;
  }
  __shared__ float rs[4][64], rss[4][64];
  rs[g][lane] = s; rss[g][lane] = ss;
  __syncthreads();
  if (g == 0){
    s  = rs[0][lane]+rs[1][lane]+rs[2][lane]+rs[3][lane];
    ss = rss[0][lane]+rss[1][lane]+rss[2][lane]+rss[3][lane];
    psum[(size_t)blockIdx.x*64 + lane] = s;
    psumsq[(size_t)blockIdx.x*64 + lane] = ss;
  }
}

// ---- elementwise: x_out[p,o] = lrelu(s*(s>=0?vmax:vmin)+t) -> xcat[:, ofs:ofs+64]
__global__ void gapply_kernel(const float* __restrict__ vmax, const float* __restrict__ vmin,
                              const float* __restrict__ scale, const float* __restrict__ shift,
                              float* __restrict__ xcat, int ofs){
  int i = blockIdx.x*256 + threadIdx.x;
  int p = i >> 6, o = i & 63;
  float s = scale[o];
  float v = (s >= 0.f) ? vmax[i] : vmin[i];
  xcat[(size_t)p*192 + ofs + o] = lrelu(s*v + shift[o]);
}

// ---- point-major matmul, 128p x 64o tile, 8x4 acc/thread (conv5).
// 32-c staging chunks: LDS 26 KB; launch_bounds(256,2) keeps VGPR cap high
// (no spill). Per-element FMA chain one ascending-c += sequence -> bit-identical.
__global__ void __launch_bounds__(256, 2)
mm_kernel(const float* __restrict__ in, int inStride, int inOfs,
          const float* __restrict__ W, int wStride,
          float* __restrict__ out, int outStride,
          const float* __restrict__ bias, int O, int I,
          const float* __restrict__ bnScale, const float* __restrict__ bnShift){
  __shared__ float As[32*AS_STRIDE + 64];
  __shared__ float Ws[32*WS_STRIDE + 64];
  int tid = threadIdx.x;
  int p0 = blockIdx.x*128, o0 = blockIdx.y*64;
  int psub = (tid >> 4)*8, osub = (tid & 15)*4;
  int cgrp = (tid & 7)*4;
  float acc[8][4] = {};
  for (int cc = 0; cc < I; cc += 32){
    float4 sc4 = make_float4(1.f,1.f,1.f,1.f), sh4 = make_float4(0.f,0.f,0.f,0.f);
    if (bnScale){
      sc4 = *(const float4*)(bnScale + cc + cgrp);
      sh4 = *(const float4*)(bnShift + cc + cgrp);
    }
    float4 vin[4], vw[2];
    #pragma unroll
    for (int j = 0; j < 4; ++j){
      int row = (tid + 256*j) >> 3;          // 0..127
      vin[j] = *(const float4*)(in + (size_t)(p0+row)*inStride + inOfs + cc + cgrp);
    }
    #pragma unroll
    for (int j = 0; j < 2; ++j){
      int row = (tid + 256*j) >> 3;          // 0..63
      vw[j] = *(const float4*)(W + (size_t)(o0+row)*wStride + cc + cgrp);
    }
    if (cc) __syncthreads();                 // WAR barrier overlaps loads above
    #pragma unroll
    for (int j = 0; j < 4; ++j){
      int row = (tid + 256*j) >> 3, c4 = cgrp;
      float4 v = vin[j];
      if (bnScale){
        v.x = lrelu(v.x*sc4.x + sh4.x); v.y = lrelu(v.y*sc4.y + sh4.y);
        v.z = lrelu(v.z*sc4.z + sh4.z); v.w = lrelu(v.w*sc4.w + sh4.w);
      }
      As[(c4+0)*AS_STRIDE+SKEW(c4+0)+row]=v.x; As[(c4+1)*AS_STRIDE+SKEW(c4+1)+row]=v.y;
      As[(c4+2)*AS_STRIDE+SKEW(c4+2)+row]=v.z; As[(c4+3)*AS_STRIDE+SKEW(c4+3)+row]=v.w;
    }
    #pragma unroll
    for (int j = 0; j < 2; ++j){
      int row = (tid + 256*j) >> 3, c4 = cgrp;
      float4 v = vw[j];
      Ws[(c4+0)*WS_STRIDE+SKEW(c4+0)+row]=v.x; Ws[(c4+1)*WS_STRIDE+SKEW(c4+1)+row]=v.y;
      Ws[(c4+2)*WS_STRIDE+SKEW(c4+2)+row]=v.z; Ws[(c4+3)*WS_STRIDE+SKEW(c4+3)+row]=v.w;
    }
    __syncthreads();
    for (int c = 0; c < 32; ++c){
      const float* arow = &As[c*AS_STRIDE + SKEW(c)];
      const float* brow = &Ws[c*WS_STRIDE + SKEW(c)];
      float4 a0 = *(const float4*)&arow[psub];
      float4 a1 = *(const float4*)&arow[psub + 4];
      float4 bb = *(const float4*)&brow[osub];
      float av[8] = {a0.x,a0.y,a0.z,a0.w,a1.x,a1.y,a1.z,a1.w};
      float bv[4] = {bb.x,bb.y,bb.z,bb.w};
      #pragma unroll
      for (int i = 0; i < 8; ++i)
        #pragma unroll
        for (int j = 0; j < 4; ++j)
          acc[i][j] += av[i]*bv[j];
    }
  }
  int bIdx = p0 >> 12;
  float bb0=0.f, bb1=0.f, bb2=0.f, bb3=0.f;
  if (bias){
    bb0 = bias[bIdx*O + o0 + osub + 0];
    bb1 = bias[bIdx*O + o0 + osub + 1];
    bb2 = bias[bIdx*O + o0 + osub + 2];
    bb3 = bias[bIdx*O + o0 + osub + 3];
  }
  #pragma unroll
  for (int i = 0; i < 8; ++i){
    float4 w;
    w.x = acc[i][0]+bb0; w.y = acc[i][1]+bb1; w.z = acc[i][2]+bb2; w.w = acc[i][3]+bb3;
    *(float4*)(out + (size_t)(p0+psub+i)*outStride + o0 + osub) = w;
  }
}

// ---- point-major matmul, 64p x 64o tile, 4x4 acc/thread (conv6/conv7).
// 32-c staging chunks: LDS 17.9 KB -> 4+ blocks/CU. Same ascending-c
// per-element FMA chain -> bit-identical outputs.
__global__ void __launch_bounds__(256, 2)
mm64_kernel(const float* __restrict__ in, int inStride, int inOfs,
            const float* __restrict__ W, int wStride,
            float* __restrict__ out, int outStride,
            int O, int I,
            const float* __restrict__ bnScale, const float* __restrict__ bnShift){
  __shared__ float As[32*WS_STRIDE + 64];
  __shared__ float Ws[32*WS_STRIDE + 64];
  int tid = threadIdx.x;
  int p0 = blockIdx.x*64, o0 = blockIdx.y*64;
  int psub = (tid >> 4)*4, osub = (tid & 15)*4;
  int cgrp = (tid & 7)*4;
  float acc[4][4] = {};
  for (int cc = 0; cc < I; cc += 32){
    float4 sc4 = make_float4(1.f,1.f,1.f,1.f), sh4 = make_float4(0.f,0.f,0.f,0.f);
    if (bnScale){
      sc4 = *(const float4*)(bnScale + cc + cgrp);
      sh4 = *(const float4*)(bnShift + cc + cgrp);
    }
    float4 vin[2], vw[2];
    #pragma unroll
    for (int j = 0; j < 2; ++j){
      int row = (tid + 256*j) >> 3;     // 0..63
      vin[j] = *(const float4*)(in + (size_t)(p0+row)*inStride + inOfs + cc + cgrp);
      vw[j]  = *(const float4*)(W + (size_t)(o0+row)*wStride + cc + cgrp);
    }
    if (cc) __syncthreads();            // WAR barrier overlaps loads above
    #pragma unroll
    for (int j = 0; j < 2; ++j){
      int row = (tid + 256*j) >> 3, c4 = cgrp;
      float4 v = vin[j];
      if (bnScale){
        v.x = lrelu(v.x*sc4.x + sh4.x); v.y = lrelu(v.y*sc4.y + sh4.y);
        v.z = lrelu(v.z*sc4.z + sh4.z); v.w = lrelu(v.w*sc4.w + sh4.w);
      }
      As[(c4+0)*WS_STRIDE+SKEW(c4+0)+row]=v.x; As[(c4+1)*WS_STRIDE+SKEW(c4+1)+row]=v.y;
      As[(c4+2)*WS_STRIDE+SKEW(c4+2)+row]=v.z; As[(c4+3)*WS_STRIDE+SKEW(c4+3)+row]=v.w;
      float4 w = vw[j];
      Ws[(c4+0)*WS_STRIDE+SKEW(c4+0)+row]=w.x; Ws[(c4+1)*WS_STRIDE+SKEW(c4+1)+row]=w.y;
      Ws[(c4+2)*WS_STRIDE+SKEW(c4+2)+row]=w.z; Ws[(c4+3)*WS_STRIDE+SKEW(c4+3)+row]=w.w;
    }
    __syncthreads();
    for (int c = 0; c < 32; ++c){
      const float* arow = &As[c*WS_STRIDE + SKEW(c)];
      const float* brow = &Ws[c*WS_STRIDE + SKEW(c)];
      float4 a0 = *(const float4*)&arow[psub];
      float4 bb = *(const float4*)&brow[osub];
      float av[4] = {a0.x,a0.y,a0.z,a0.w};
      float bv[4] = {bb.x,bb.y,bb.z,bb.w};
      #pragma unroll
      for (int i = 0; i < 4; ++i)
        #pragma unroll
        for (int j = 0; j < 4; ++j)
          acc[i][j] += av[i]*bv[j];
    }
  }
  #pragma unroll
  for (int i = 0; i < 4; ++i){
    float4 w;
    w.x = acc[i][0]; w.y = acc[i][1]; w.z = acc[i][2]; w.w = acc[i][3];
    *(float4*)(out + (size_t)(p0+psub+i)*outStride + o0 + osub) = w;
  }
}

// ---- conv4 FUSED with stats: computes the 128x128 r4 tile in registers, then
// reduces in-block to per-channel sum/sumsq partials + per-(tile,ch) max/min.
// r4 is NEVER materialized. 32-c staging chunks (LDS 34.3 KB -> 4 blocks/CU).
__global__ void __launch_bounds__(256, 2)
conv4stats_kernel(const float* __restrict__ xcat, const float* __restrict__ W4,
                  float* __restrict__ psum, float* __restrict__ psumsq,
                  float* __restrict__ pmax, float* __restrict__ pmin){
  __shared__ float As[32*AS_STRIDE + 64];
  __shared__ float Ws[32*AS_STRIDE + 64];
  int tid = threadIdx.x;
  int p0 = blockIdx.x*128, o0 = blockIdx.y*128;
  int pA = (tid >> 4)*4, oB = (tid & 15)*4;
  int cgrp = (tid & 7)*4;
  float acc[8][8] = {};
  for (int h = 0; h < 2; ++h){
    int cb = h*32;
    float4 vin[4], vw[4];
    #pragma unroll
    for (int j = 0; j < 4; ++j){
      int row = (tid + 256*j) >> 3;          // 0..127
      vin[j] = *(const float4*)(xcat + (size_t)(p0+row)*192 + 128 + cb + cgrp);
      vw[j]  = *(const float4*)(W4 + (size_t)(o0+row)*64 + cb + cgrp);
    }
    if (h) __syncthreads();                  // WAR
    #pragma unroll
    for (int j = 0; j < 4; ++j){
      int row = (tid + 256*j) >> 3, c4 = cgrp;
      float4 v = vin[j];
      As[(c4+0)*AS_STRIDE+SKEW(c4+0)+row]=v.x; As[(c4+1)*AS_STRIDE+SKEW(c4+1)+row]=v.y;
      As[(c4+2)*AS_STRIDE+SKEW(c4+2)+row]=v.z; As[(c4+3)*AS_STRIDE+SKEW(c4+3)+row]=v.w;
      float4 w = vw[j];
      Ws[(c4+0)*AS_STRIDE+SKEW(c4+0)+row]=w.x; Ws[(c4+1)*AS_STRIDE+SKEW(c4+1)+row]=w.y;
      Ws[(c4+2)*AS_STRIDE+SKEW(c4+2)+row]=w.z; Ws[(c4+3)*AS_STRIDE+SKEW(c4+3)+row]=w.w;
    }
    __syncthreads();                         // RAW
    for (int c = 0; c < 32; ++c){
      const float* arow = &As[c*AS_STRIDE + SKEW(c)];
      const float* brow = &Ws[c*AS_STRIDE + SKEW(c)];
      float4 a0 = *(const float4*)&arow[pA];
      float4 a1 = *(const float4*)&arow[pA + 64];
      float4 b0 = *(const float4*)&brow[oB];
      float4 b1 = *(const float4*)&brow[oB + 64];
      float av[8] = {a0.x,a0.y,a0.z,a0.w,a1.x,a1.y,a1.z,a1.w};
      float bv[8] = {b0.x,b0.y,b0.z,b0.w,b1.x,b1.y,b1.z,b1.w};
      #pragma unroll
      for (int i = 0; i < 8; ++i)
        #pragma unroll
        for (int j = 0; j < 8; ++j)
          acc[i][j] += av[i]*bv[j];
    }
  }
  // per-thread column partials over its 8 rows (fixed order i=0..7)
  float cs[8], cq[8], cmx[8], cmn[8];
  #pragma unroll
  for (int j = 0; j < 8; ++j){
    float s = 0.f, q = 0.f, mx = -INFINITY, mn = INFINITY;
    #pragma unroll
    for (int i = 0; i < 8; ++i){
      float v = acc[i][j];
      s += v; q += v*v; mx = fmaxf(mx, v); mn = fminf(mn, v);
    }
    cs[j]=s; cq[j]=q; cmx[j]=mx; cmn[j]=mn;
  }
  __syncthreads();   // done reading As/Ws; reuse as scratch (4096 <= 4288 floats)
  int r = tid >> 4;
  #pragma unroll
  for (int j = 0; j < 8; ++j){
    int col = (j < 4) ? (oB + j) : (64 + oB + (j-4));
    As[r*128 + col]        = cs[j];
    As[2048 + r*128 + col] = cq[j];
    Ws[r*128 + col]        = cmx[j];
    Ws[2048 + r*128 + col] = cmn[j];
  }
  __syncthreads();
  if (tid < 128){
    float ts = 0.f, tq = 0.f, tm = -INFINITY, tn = INFINITY;
    for (int rr = 0; rr < 16; ++rr){
      ts += As[rr*128 + tid];
      tq += As[2048 + rr*128 + tid];
      tm = fmaxf(tm, Ws[rr*128 + tid]);
      tn = fminf(tn, Ws[2048 + rr*128 + tid]);
    }
    size_t slot = (size_t)blockIdx.x*512 + o0 + tid;
    psum[slot] = ts; psumsq[slot] = tq; pmax[slot] = tm; pmin[slot] = tn;
  }
}

// lrelu(s*v+t) monotone in v: use max if s>=0 else min  (32 tiles per batch)
__global__ void x6v_kernel(const float* __restrict__ pmax, const float* __restrict__ pmin,
                           const float* __restrict__ scale, const float* __restrict__ shift,
                           float* __restrict__ x6v){
  int t = blockIdx.x*256 + threadIdx.x;
  int b = t >> 9, o = t & 511;
  float mx = -INFINITY, mn = INFINITY;
  for (int pt = b*32; pt < b*32+32; ++pt){
    mx = fmaxf(mx, pmax[(size_t)pt*512 + o]);
    mn = fminf(mn, pmin[(size_t)pt*512 + o]);
  }
  float s = scale[o];
  float v = (s >= 0.f) ? mx : mn;
  x6v[t] = lrelu(s*v + shift[o]);
}

// bias5[b,o] = sum_c W5[o, 192+c] * x6v[b,c]   (the broadcast part of the concat)
__global__ void bias5_kernel(const float* __restrict__ W5, const float* __restrict__ x6v,
                             float* __restrict__ b5){
  __shared__ float xl[512];
  int tid = threadIdx.x;
  int t = blockIdx.x*256 + tid;
  int b = t >> 9, o = t & 511;
  for (int i = tid; i < 512; i += 256) xl[i] = x6v[(b<<9) + i];
  __syncthreads();
  const float* wr = W5 + (size_t)o*704 + 192;
  float acc = 0.f;
  for (int c = 0; c < 512; ++c) acc += wr[c]*xl[c];
  b5[t] = acc;
}

// ---- conv8 (128->2) + bias over raw r7 with BN7+lrelu applied inline
__global__ void conv8_kernel(const float* __restrict__ r7, const float* __restrict__ W8,
                             const float* __restrict__ bias8,
                             const float* __restrict__ scale, const float* __restrict__ shift,
                             float* __restrict__ out){
  __shared__ float Wl[256];
  __shared__ float scl[128], shl[128];
  int tid = threadIdx.x;
  Wl[tid] = W8[tid];
  if (tid < 128){ scl[tid] = scale[tid]; shl[tid] = shift[tid]; }
  __syncthreads();
  int p = blockIdx.x*256 + tid;
  int b = p >> 12, n = p & 4095;
  const float4* row = (const float4*)(r7 + (size_t)p*128);
  float a0 = 0.f, a1 = 0.f;
  #pragma unroll
  for (int i = 0; i < 32; ++i){
    float4 v = row[i];
    v.x = lrelu(v.x*scl[i*4+0] + shl[i*4+0]);
    v.y = lrelu(v.y*scl[i*4+1] + shl[i*4+1]);
    v.z = lrelu(v.z*scl[i*4+2] + shl[i*4+2]);
    v.w = lrelu(v.w*scl[i*4+3] + shl[i*4+3]);
    a0 += v.x*Wl[i*4] + v.y*Wl[i*4+1] + v.z*Wl[i*4+2] + v.w*Wl[i*4+3];
    a1 += v.x*Wl[128+i*4] + v.y*Wl[128+i*4+1] + v.z*Wl[128+i*4+2] + v.w*Wl[128+i*4+3];
  }
  out[(size_t)(b*2+0)*NN + n] = a0 + bias8[0];
  out[(size_t)(b*2+1)*NN + n] = a1 + bias8[1];
}

extern "C" void kernel_launch(void* const* d_in, const int* in_sizes, int n_in,
                              void* d_out, int out_size, void* d_ws, size_t ws_size,
                              hipStream_t stream){
  const float* x     = (const float*)d_in[0];
  const float* W1    = (const float*)d_in[1];
  const float* W2    = (const float*)d_in[2];
  const float* W3    = (const float*)d_in[3];
  const float* W4    = (const float*)d_in[4];
  const float* W5    = (const float*)d_in[5];
  const float* W6    = (const float*)d_in[6];
  const float* W7    = (const float*)d_in[7];
  const float* W8    = (const float*)d_in[8];
  const float* bias8 = (const float*)d_in[9];
  const float* gamma[8]; const float* beta[8];
  for (int i = 1; i <= 7; ++i){
    gamma[i] = (const float*)d_in[10 + 2*(i-1)];
    beta[i]  = (const float*)d_in[11 + 2*(i-1)];
  }
  float* out = (float*)d_out;

  float* ws = (float*)d_ws;
  size_t off = 0;
  float* xcat  = ws + off; off += (size_t)NPT*192;   // x1|x2|x3 packed, stride 192
  float* U     = ws + off; off += (size_t)NPT*64;
  float* T     = ws + off; off += (size_t)NPT*64;
  float* xx    = ws + off; off += NPT;
  int*   idx   = (int*)(ws + off); off += (size_t)NPT*KK;
  float* psum  = ws + off; off += 128*512;
  float* psumsq= ws + off; off += 128*512;
  float* pmax  = ws + off; off += 128*512;
  float* pmin  = ws + off; off += 128*512;
  float* scale = ws + off; off += 512;
  float* shift = ws + off; off += 512;
  float* x6v   = ws + off; off += 2048;
  float* b5    = ws + off; off += 2048;
  float* big   = ws + off;   // time-shared: dist (knn) / vmax|vmin (gather) / r5|r6|r7
  float* dist  = big;                               // 16.8M floats (one batch)
  float* vmaxB = big;                               // NPT*64, live only between knn rounds
  float* vminB = big + (size_t)NPT*64;
  float* r5    = big;
  float* r6    = big + (size_t)NPT*512;
  float* r7    = big + (size_t)NPT*512 + (size_t)NPT*256;
  // gmax overlays U|T (dead during knn): 4096 rows x 512 groups u32 = 2M words
  unsigned* gmaxU = (unsigned*)U;

  // ---- stage 1: conv1 + BN(train stats) + lrelu -> x1 (xcat[:,0:64])
  conv1_kernel<<<NPT/4, 256, 0, stream>>>(x, W1, xcat);
  stats_pm_kernel<<<dim3(1,64), 256, 0, stream>>>(xcat, 192, 0, psum, psumsq, 64);
  bn_finalize_kernel<<<1, 64, 0, stream>>>(psum, psumsq, 64, gamma[1], beta[1], scale, shift, 1.f/16384.f, 64);
  apply_bn_kernel<<<NPT*64/256, 256, 0, stream>>>(xcat, 192, 0, 6, scale, shift);

  // ---- knn on x1 (triangular dist+gmax; filtered exact top-20)
  xx_kernel<<<NPT/256, 256, 0, stream>>>(xcat, 192, 0, xx);
  for (int b = 0; b < BB; ++b){
    dist_kernel<<<dim3(32,32), 256, 0, stream>>>(xcat, 0, xx, dist, gmaxU, b);
    topk_kernel<<<NN/4, 256, 0, stream>>>(dist, gmaxU, idx + (size_t)b*NN*KK);
  }

  // ---- stage 2: edge-conv (W2): single gather pass (stats + vmax/vmin), then elementwise
  ut_kernel<<<NPT/4, 256, 0, stream>>>(xcat, 0, W2, U, T);
  gather_kernel<<<256, 256, 0, stream>>>(U, T, idx, psum, psumsq, vmaxB, vminB);
  bn_finalize_kernel<<<1, 64, 0, stream>>>(psum, psumsq, 256, gamma[2], beta[2], scale, shift, 1.f/327680.f, 64);
  gapply_kernel<<<NPT*64/256, 256, 0, stream>>>(vmaxB, vminB, scale, shift, xcat, 64);

  // ---- knn on x2
  xx_kernel<<<NPT/256, 256, 0, stream>>>(xcat, 192, 64, xx);
  for (int b = 0; b < BB; ++b){
    dist_kernel<<<dim3(32,32), 256, 0, stream>>>(xcat, 64, xx, dist, gmaxU, b);
    topk_kernel<<<NN/4, 256, 0, stream>>>(dist, gmaxU, idx + (size_t)b*NN*KK);
  }

  // ---- stage 3: edge-conv (W3) -> x3
  ut_kernel<<<NPT/4, 256, 0, stream>>>(xcat, 64, W3, U, T);
  gather_kernel<<<256, 256, 0, stream>>>(U, T, idx, psum, psumsq, vmaxB, vminB);
  bn_finalize_kernel<<<1, 64, 0, stream>>>(psum, psumsq, 256, gamma[3], beta[3], scale, shift, 1.f/327680.f, 64);
  gapply_kernel<<<NPT*64/256, 256, 0, stream>>>(vmaxB, vminB, scale, shift, xcat, 128);

  // ---- stage 4: conv4 fused with stats (r4 never materialized)
  conv4stats_kernel<<<dim3(NPT/128, 4), 256, 0, stream>>>(xcat, W4, psum, psumsq, pmax, pmin);
  bn_finalize_kernel<<<1, 512, 0, stream>>>(psum, psumsq, 128, gamma[4], beta[4], scale, shift, 1.f/16384.f, 512);
  x6v_kernel<<<8, 256, 0, stream>>>(pmax, pmin, scale, shift, x6v);
  bias5_kernel<<<8, 256, 0, stream>>>(W5, x6v, b5);

  // ---- stage 5: conv5 (704->512) via mm_kernel 64-o tiles: grid 1024 blocks
  mm_kernel<<<dim3(NPT/128, 8), 256, 0, stream>>>(xcat, 192, 0, W5, 704, r5, 512, b5, 512, 192, nullptr, nullptr);
  stats_pm_kernel<<<dim3(8,64), 256, 0, stream>>>(r5, 512, 0, psum, psumsq, 512);
  bn_finalize_kernel<<<1, 512, 0, stream>>>(psum, psumsq, 64, gamma[5], beta[5], scale, shift, 1.f/16384.f, 512);

  // ---- stage 6: conv6 (512->256), BN5+lrelu on load; r6 stays RAW.
  mm64_kernel<<<dim3(NPT/64, 4), 256, 0, stream>>>(r5, 512, 0, W6, 512, r6, 256, 256, 512, scale, shift);
  stats_pm_kernel<<<dim3(4,64), 256, 0, stream>>>(r6, 256, 0, psum, psumsq, 256);
  bn_finalize_kernel<<<1, 256, 0, stream>>>(psum, psumsq, 64, gamma[6], beta[6], scale, shift, 1.f/16384.f, 256);

  // ---- stage 7: conv7 (256->128), BN6+lrelu on load; r7 stays RAW.
  mm64_kernel<<<dim3(NPT/64, 2), 256, 0, stream>>>(r6, 256, 0, W7, 256, r7, 128, 128, 256, scale, shift);
  stats_pm_kernel<<<dim3(2,64), 256, 0, stream>>>(r7, 128, 0, psum, psumsq, 128);
  bn_finalize_kernel<<<1, 128, 0, stream>>>(psum, psumsq, 64, gamma[7], beta[7], scale, shift, 1.f/16384.f, 128);

  // ---- stage 8: conv8 (128->2) + bias, BN7+lrelu applied inline
  conv8_kernel<<<NPT/256, 256, 0, stream>>>(r7, W8, bias8, scale, shift, out);
}